// Round 12
// baseline (733.548 us; speedup 1.0000x reference)
//
#include <hip/hip_runtime.h>
#include <hip/hip_bf16.h>

#define NB 16
#define N2V 618
#define N3V 2466
#define FEAT 963
#define HID 192
#define IN_DIM 1163
#define KPAD2 1216         // 1163 padded to 38*32
#define ETILES 38
#define EHALF 19
#define MTOT (NB * N3V)    // 39456
#define M2   (NB * N2V)    // 9888

typedef __attribute__((ext_vector_type(8))) short bf16x8;
typedef __attribute__((ext_vector_type(4))) float f32x4;

__device__ __forceinline__ float bf2f(ushort u) {
    return __uint_as_float(((unsigned)u) << 16);
}
__device__ __forceinline__ ushort f2bf(float f) {   // round-to-nearest-even
    unsigned u = __float_as_uint(f);
    return (ushort)((u + 0x7FFFu + ((u >> 16) & 1u)) >> 16);
}
// bijective XCD-chunk swizzle (m204)
__device__ __forceinline__ int xcd_swz(int bid, int G) {
    int q = G >> 3, r = G & 7;
    int xcd = bid & 7, slot = bid >> 3;
    return (xcd < r) ? xcd * (q + 1) + slot : r * (q + 1) + (xcd - r) * q + slot;
}

// ---------------------------------------------------------------------------
// q,k,v projections: mv grade-1 only -> rows 1..3 of W
// ---------------------------------------------------------------------------
__global__ void qkv_kernel(const float* __restrict__ x2,
                           const float* __restrict__ Wq, const float* __restrict__ bq,
                           const float* __restrict__ Wk, const float* __restrict__ bk,
                           const float* __restrict__ Wv, const float* __restrict__ bv,
                           float* __restrict__ q, float* __restrict__ k, float* __restrict__ v)
{
    int idx = blockIdx.x * 256 + threadIdx.x;
    if (idx >= M2) return;
    float c0 = x2[idx * 3 + 0], c1 = x2[idx * 3 + 1], c2 = x2[idx * 3 + 2];
#pragma unroll
    for (int d = 0; d < 8; ++d) {
        q[idx * 8 + d] = bq[d] + c0 * Wq[8 + d] + c1 * Wq[16 + d] + c2 * Wq[24 + d];
        k[idx * 8 + d] = bk[d] + c0 * Wk[8 + d] + c1 * Wk[16 + d] + c2 * Wk[24 + d];
        v[idx * 8 + d] = bv[d] + c0 * Wv[8 + d] + c1 * Wv[16 + d] + c2 * Wv[24 + d];
    }
}

// ---------------------------------------------------------------------------
// attention: block = (batch, 64 queries); K,V staged in LDS (39.6KB);
// 4 lanes per query, online softmax, shfl merge across the 4 sub-lanes.
// ---------------------------------------------------------------------------
__global__ __launch_bounds__(256) void attn_kernel2(const float* __restrict__ q,
                                                    const float* __restrict__ k,
                                                    const float* __restrict__ v,
                                                    float* __restrict__ att)
{
    __shared__ float4 kv[N2V * 4];            // K: [0,2*N2V), V: [2*N2V,4*N2V)
    int b = blockIdx.x, qb = blockIdx.y;
    const float4* k4 = (const float4*)(k + (size_t)b * N2V * 8);
    const float4* v4 = (const float4*)(v + (size_t)b * N2V * 8);
    for (int i = threadIdx.x; i < N2V * 2; i += 256) {
        kv[i] = k4[i];
        kv[N2V * 2 + i] = v4[i];
    }
    __syncthreads();

    int ql = threadIdx.x >> 2, sub = threadIdx.x & 3;
    int qi = qb * 64 + ql;
    bool valid = qi < N2V;
    float qv[8];
#pragma unroll
    for (int d = 0; d < 8; ++d) qv[d] = 0.f;
    if (valid) {
#pragma unroll
        for (int d = 0; d < 8; ++d) qv[d] = q[((size_t)b * N2V + qi) * 8 + d];
    }

    const float scale = 0.35355339059327373f;
    float m = -3.0e38f, lsum = 0.f, acc[8];
#pragma unroll
    for (int d = 0; d < 8; ++d) acc[d] = 0.f;

    for (int kk = sub; kk < N2V; kk += 4) {
        float4 k0 = kv[kk * 2], k1 = kv[kk * 2 + 1];
        float s = qv[0] * k0.x + qv[1] * k0.y + qv[2] * k0.z + qv[3] * k0.w
                + qv[4] * k1.x + qv[5] * k1.y + qv[6] * k1.z + qv[7] * k1.w;
        s *= scale;
        float nm = fmaxf(m, s);
        float corr = __expf(m - nm);
        float p = __expf(s - nm);
        lsum = lsum * corr + p;
        float4 v0 = kv[N2V * 2 + kk * 2], v1 = kv[N2V * 2 + kk * 2 + 1];
        acc[0] = acc[0] * corr + p * v0.x; acc[1] = acc[1] * corr + p * v0.y;
        acc[2] = acc[2] * corr + p * v0.z; acc[3] = acc[3] * corr + p * v0.w;
        acc[4] = acc[4] * corr + p * v1.x; acc[5] = acc[5] * corr + p * v1.y;
        acc[6] = acc[6] * corr + p * v1.z; acc[7] = acc[7] * corr + p * v1.w;
        m = nm;
    }
#pragma unroll
    for (int o = 1; o <= 2; o <<= 1) {
        float m2 = __shfl_xor(m, o);
        float l2 = __shfl_xor(lsum, o);
        float nm = fmaxf(m, m2);
        float c1 = __expf(m - nm), c2 = __expf(m2 - nm);
        lsum = lsum * c1 + l2 * c2;
#pragma unroll
        for (int d = 0; d < 8; ++d) {
            float a2 = __shfl_xor(acc[d], o);
            acc[d] = acc[d] * c1 + a2 * c2;
        }
        m = nm;
    }
    if (valid && sub == 0) {
#pragma unroll
        for (int d = 0; d < 8; ++d)
            att[((size_t)b * N2V + qi) * 8 + d] = acc[d] / lsum;
    }
}

// ---------------------------------------------------------------------------
// adjacency prep: <=6 (col,val) per row (sorted), plus entry-layer expansion
// through the unpool midpoints (adj@Up, <=12 gathers) and self parent pair.
// ---------------------------------------------------------------------------
__global__ void adj_prep(const float* __restrict__ adj, const int* __restrict__ unpool,
                         int* __restrict__ cols, float* __restrict__ vals,
                         int* __restrict__ eidx, float* __restrict__ ew,
                         int* __restrict__ sidx)
{
    int m = blockIdx.x;
    __shared__ int cnt;
    __shared__ int lc[8];
    __shared__ float lv[8];
    if (threadIdx.x == 0) cnt = 0;
    __syncthreads();
    for (int c = threadIdx.x; c < N3V; c += 256) {
        float a = adj[(size_t)m * N3V + c];
        if (a != 0.f) {
            int p = atomicAdd(&cnt, 1);
            if (p < 6) { lc[p] = c; lv[p] = a; }
        }
    }
    __syncthreads();
    if (threadIdx.x == 0) {
        int n = cnt < 6 ? cnt : 6;
        for (int i = 1; i < n; ++i) {
            int ci = lc[i]; float vi = lv[i]; int j = i - 1;
            while (j >= 0 && lc[j] > ci) { lc[j + 1] = lc[j]; lv[j + 1] = lv[j]; --j; }
            lc[j + 1] = ci; lv[j + 1] = vi;
        }
        int ne = 0;
        for (int i = 0; i < 6; ++i) {
            int c = (i < n) ? lc[i] : 0;
            float w = (i < n) ? lv[i] : 0.f;
            cols[m * 6 + i] = c;
            vals[m * 6 + i] = w;
            if (i < n) {
                if (c < N2V) { eidx[m * 12 + ne] = c; ew[m * 12 + ne] = w; ++ne; }
                else {
                    int jj = c - N2V;
                    eidx[m * 12 + ne] = unpool[2 * jj];     ew[m * 12 + ne] = 0.5f * w; ++ne;
                    eidx[m * 12 + ne] = unpool[2 * jj + 1]; ew[m * 12 + ne] = 0.5f * w; ++ne;
                }
            }
        }
        for (; ne < 12; ++ne) { eidx[m * 12 + ne] = 0; ew[m * 12 + ne] = 0.f; }
        if (m < N2V) { sidx[m * 2] = m; sidx[m * 2 + 1] = -1; }
        else {
            int j = m - N2V;
            sidx[m * 2] = unpool[2 * j];
            sidx[m * 2 + 1] = unpool[2 * j + 1];
        }
    }
}

// ---------------------------------------------------------------------------
// F[bn][k] bf16: concat(x[963], xh[192], att[8], zeros) padded to KPAD2
// ---------------------------------------------------------------------------
__global__ void build_F(const float* __restrict__ x, const float* __restrict__ xh,
                        const float* __restrict__ att, ushort* __restrict__ F)
{
    int bn = blockIdx.x;
    for (int k = threadIdx.x; k < KPAD2; k += 256) {
        float v = 0.f;
        if (k < FEAT) v = x[(size_t)bn * FEAT + k];
        else if (k < FEAT + HID) v = xh[(size_t)bn * HID + (k - FEAT)];
        else if (k < IN_DIM) v = att[(size_t)bn * 8 + (k - FEAT - HID)];
        F[(size_t)bn * KPAD2 + k] = f2bf(v);
    }
}

// ---------------------------------------------------------------------------
// weight prep via LDS tile transpose (coalesced reads AND writes).
// blocks 0..455: entry tiles (38 k-tiles x 12 n-tiles) -> wt_e[384][KPAD2]
// blocks 456..1391: res tiles (13 layers x 12 k2-tiles x 6 n-tiles)
// 256 thr = 32x8; each thread moves 4 elements.
// ---------------------------------------------------------------------------
#define ENT_TILES (38 * 12)      // 456
#define RES_TILES (13 * 12 * 6)  // 936
__global__ void prep_wt_all(const float* __restrict__ W_in, const float* __restrict__ loopW_in,
                            const float* __restrict__ res_W, const float* __restrict__ res_loopW,
                            const float* __restrict__ W_out, const float* __restrict__ loopW_out,
                            ushort* __restrict__ wt_e, ushort* __restrict__ wt_r)
{
    __shared__ float tile[32][33];
    int blk = blockIdx.x;
    int lx = threadIdx.x & 31, ly = threadIdx.x >> 5;

    if (blk < ENT_TILES) {
        int tk = blk % 38, tn = blk / 38;
        int k0 = tk * 32, n0 = tn * 32;
#pragma unroll
        for (int i = 0; i < 4; ++i) {
            int k = k0 + ly + i * 8, n = n0 + lx;
            float v = 0.f;
            if (k < IN_DIM) v = (n < 192) ? W_in[k * 192 + n] : loopW_in[k * 192 + (n - 192)];
            tile[ly + i * 8][lx] = v;
        }
        __syncthreads();
#pragma unroll
        for (int i = 0; i < 4; ++i) {
            int n = n0 + ly + i * 8, k = k0 + lx;
            wt_e[(size_t)n * KPAD2 + k] = f2bf(tile[lx][ly + i * 8]);
        }
    } else {
        blk -= ENT_TILES;
        int l = blk / 72;
        int rem = blk % 72;
        int tk = rem % 12, tn = rem / 12;
        const float* W = (l < 12) ? (res_W + (size_t)l * 192 * 192) : W_out;
        const float* L = (l < 12) ? (res_loopW + (size_t)l * 192 * 192) : loopW_out;
        int k0 = tk * 32, n0 = tn * 32;
#pragma unroll
        for (int i = 0; i < 4; ++i) {
            int k2 = k0 + ly + i * 8, n = n0 + lx;
            float v = (k2 < 192) ? W[k2 * 192 + n] : L[(k2 - 192) * 192 + n];
            tile[ly + i * 8][lx] = v;
        }
        __syncthreads();
        ushort* wt = wt_r + (size_t)l * 192 * 384;
#pragma unroll
        for (int i = 0; i < 4; ++i) {
            int n = n0 + ly + i * 8, k2 = k0 + lx;
            wt[(size_t)n * 384 + k2] = f2bf(tile[lx][ly + i * 8]);
        }
    }
}

// ---------------------------------------------------------------------------
// entry GEMM, K-split x2: u2[M2,384] = F[M2,KPAD2] @ Wt^T.
// 512 thr (8 waves); block 64 rows x 192 cols; grid (155, 2).
// wave w: w&3 -> col group (4m x 3n), w>>2 -> k half (19 tiles each).
// High waves dump f32 partials to LDS; low waves add + store.
// ---------------------------------------------------------------------------
__global__ __launch_bounds__(512) void gemm_entry(
    const ushort* __restrict__ F, const ushort* __restrict__ Wt,
    ushort* __restrict__ u2)
{
    __shared__ float part[64 * 192];   // 48 KB

    int tid = threadIdx.x;
    int wave = tid >> 6, lane = tid & 63;
    int kh = wave >> 2, w4 = wave & 3;
    int lr = lane & 15, lkq = lane >> 4, lk = lkq * 8;
    int row0 = blockIdx.x * 64;
    int lnb = w4 * 48;                       // LDS/block-local col
    int nb = blockIdx.y * 192 + lnb;         // global col
    int tbeg = kh * EHALF, tend = tbeg + EHALF;

    int rows[4];
#pragma unroll
    for (int mt = 0; mt < 4; ++mt) {
        int r = row0 + mt * 16 + lr;
        rows[mt] = (r < M2) ? r : M2 - 1;
    }

    f32x4 acc[4][3];
#pragma unroll
    for (int mt = 0; mt < 4; ++mt)
#pragma unroll
        for (int nt = 0; nt < 3; ++nt) acc[mt][nt] = (f32x4){0.f, 0.f, 0.f, 0.f};

    bf16x8 a0[4], b0[3], a1[4], b1[3];
    auto LD = [&](int t, bf16x8 (&a)[4], bf16x8 (&b)[3]) {
#pragma unroll
        for (int mt = 0; mt < 4; ++mt)
            a[mt] = *(const bf16x8*)(F + (size_t)rows[mt] * KPAD2 + t * 32 + lk);
#pragma unroll
        for (int nt = 0; nt < 3; ++nt)
            b[nt] = *(const bf16x8*)(Wt + (size_t)(nb + nt * 16 + lr) * KPAD2 + t * 32 + lk);
    };
    auto MM = [&](bf16x8 (&a)[4], bf16x8 (&b)[3]) {
#pragma unroll
        for (int mt = 0; mt < 4; ++mt)
#pragma unroll
            for (int nt = 0; nt < 3; ++nt)
                acc[mt][nt] = __builtin_amdgcn_mfma_f32_16x16x32_bf16(a[mt], b[nt], acc[mt][nt], 0, 0, 0);
    };

    LD(tbeg, a0, b0);
    for (int t = tbeg; t < tend; t += 2) {
        if (t + 1 < tend) LD(t + 1, a1, b1);
        MM(a0, b0);
        if (t + 2 < tend) LD(t + 2, a0, b0);
        if (t + 1 < tend) MM(a1, b1);
    }

    int crow = lkq * 4;
    if (kh == 1) {
#pragma unroll
        for (int mt = 0; mt < 4; ++mt)
#pragma unroll
            for (int r = 0; r < 4; ++r)
#pragma unroll
                for (int nt = 0; nt < 3; ++nt)
                    part[(mt * 16 + crow + r) * 192 + lnb + nt * 16 + lr] = acc[mt][nt][r];
    }
    __syncthreads();
    if (kh == 0) {
#pragma unroll
        for (int mt = 0; mt < 4; ++mt)
#pragma unroll
            for (int r = 0; r < 4; ++r) {
                int orow = row0 + mt * 16 + crow + r;
                if (orow < M2) {
#pragma unroll
                    for (int nt = 0; nt < 3; ++nt) {
                        float s = acc[mt][nt][r] + part[(mt * 16 + crow + r) * 192 + lnb + nt * 16 + lr];
                        u2[(size_t)orow * 384 + nb + nt * 16 + lr] = f2bf(s);
                    }
                }
            }
    }
}

// ---------------------------------------------------------------------------
// entry combine: h = relu( sum_i ew*Pw[eidx] + mid(Pl over sidx) + bias )
// 192 thr = 8 rows x 24 col-groups of 8 (16B vector loads). XCD-swizzled.
// ---------------------------------------------------------------------------
__global__ void combine_entry(const ushort* __restrict__ u2, const int* __restrict__ eidx,
                              const float* __restrict__ ew, const int* __restrict__ sidx,
                              const float* __restrict__ bias, ushort* __restrict__ h)
{
    int lb = xcd_swz(blockIdx.x, gridDim.x);
    int tid = threadIdx.x;
    int rloc = tid / 24, f8 = tid % 24;
    int bm = lb * 8 + rloc;
    if (bm >= MTOT) return;
    int b = bm / N3V, n = bm % N3V;
    const ushort* base = u2 + (size_t)b * N2V * 384;

    float acc[8];
#pragma unroll
    for (int e = 0; e < 8; ++e) acc[e] = 0.f;
#pragma unroll
    for (int i = 0; i < 12; ++i) {
        float w = ew[n * 12 + i];
        bf16x8 v = *(const bf16x8*)(base + (size_t)eidx[n * 12 + i] * 384 + f8 * 8);
#pragma unroll
        for (int e = 0; e < 8; ++e) acc[e] += w * bf2f((ushort)v[e]);
    }
    int p0 = sidx[n * 2], p1 = sidx[n * 2 + 1];
    bf16x8 s0 = *(const bf16x8*)(base + (size_t)p0 * 384 + 192 + f8 * 8);
    if (p1 >= 0) {
        bf16x8 s1 = *(const bf16x8*)(base + (size_t)p1 * 384 + 192 + f8 * 8);
#pragma unroll
        for (int e = 0; e < 8; ++e) acc[e] += 0.5f * (bf2f((ushort)s0[e]) + bf2f((ushort)s1[e]));
    } else {
#pragma unroll
        for (int e = 0; e < 8; ++e) acc[e] += bf2f((ushort)s0[e]);
    }
    bf16x8 o;
#pragma unroll
    for (int e = 0; e < 8; ++e)
        o[e] = (short)f2bf(fmaxf(acc[e] + bias[f8 * 8 + e], 0.f));
    *(bf16x8*)(h + (size_t)bm * 192 + f8 * 8) = o;
}

// ---------------------------------------------------------------------------
// fused res GConv, full-K: out = act( [adj@src | src] @ Wt^T + bias )
// 512 thr, 64-row block, grid 617 (XCD-swizzled).
// Phase 0: 1536 gather tasks (exactly 3/thread, unrolled for MLP) ->
//          g staged in 24KB XOR-swizzled LDS.
// Phase 1: 8 waves = 2 m-halves x 4 col-groups; each wave 2m x 3n, full
//          K=12 tiles (t<6 A=LDS(g), t>=6 A=src rows), 2-deep pipeline.
// ACT 0: relu; ACT 1: 0.5*(hprev + relu(.)).
// ---------------------------------------------------------------------------
template <int ACT>
__global__ __launch_bounds__(512) void gconv_fused(
    const ushort* __restrict__ src, const int* __restrict__ cols,
    const float* __restrict__ vals, const ushort* __restrict__ Wt,
    const float* __restrict__ bias, const ushort* __restrict__ hprev,
    ushort* __restrict__ outp)
{
    __shared__ ushort gs[64 * 192];    // 24 KB, XOR-swizzled

    int lb = xcd_swz(blockIdx.x, gridDim.x);
    int tid = threadIdx.x;
    int row0 = lb * 64;

    // ---- phase 0: g = adj @ src for this block's 64 rows -> LDS ----
#pragma unroll
    for (int it = 0; it < 3; ++it) {
        int task = tid + it * 512;
        int r = task / 24, f8 = task % 24;
        int bm = row0 + r;
        if (bm >= MTOT) bm = MTOT - 1;
        int b = bm / N3V, m = bm % N3V;
        const ushort* hb = src + (size_t)b * N3V * 192;
        float acc[8];
#pragma unroll
        for (int e = 0; e < 8; ++e) acc[e] = 0.f;
#pragma unroll
        for (int j = 0; j < 6; ++j) {
            float w = vals[m * 6 + j];
            bf16x8 v = *(const bf16x8*)(hb + (size_t)cols[m * 6 + j] * 192 + f8 * 8);
#pragma unroll
            for (int e = 0; e < 8; ++e) acc[e] += w * bf2f((ushort)v[e]);
        }
        bf16x8 o;
#pragma unroll
        for (int e = 0; e < 8; ++e) o[e] = (short)f2bf(acc[e]);
        int byte = r * 384 + f8 * 16;
        byte ^= (r & 7) << 4;
        *(bf16x8*)((char*)gs + byte) = o;
    }
    __syncthreads();

    // ---- phase 1: full-K GEMM ----
    int wave = tid >> 6, lane = tid & 63;
    int wm = wave >> 2, wc = wave & 3;
    int lr = lane & 15, lkq = lane >> 4, lk = lkq * 8;
    int nb = wc * 48;
    int rbase = wm * 32;

    int rows[2];
#pragma unroll
    for (int mt = 0; mt < 2; ++mt) {
        int r = row0 + rbase + mt * 16 + lr;
        rows[mt] = (r < MTOT) ? r : MTOT - 1;
    }

    f32x4 acc[2][3];
#pragma unroll
    for (int mt = 0; mt < 2; ++mt)
#pragma unroll
        for (int nt = 0; nt < 3; ++nt) acc[mt][nt] = (f32x4){0.f, 0.f, 0.f, 0.f};

    bf16x8 a0[2], b0[3], a1[2], b1[3];
    auto LD = [&](int t, bf16x8 (&a)[2], bf16x8 (&b)[3]) {
        if (t < 6) {
#pragma unroll
            for (int mt = 0; mt < 2; ++mt) {
                int rr = rbase + mt * 16 + lr;
                int byte = rr * 384 + t * 64 + lkq * 16;
                byte ^= (rr & 7) << 4;
                a[mt] = *(const bf16x8*)((const char*)gs + byte);
            }
        } else {
            int kk = (t - 6) * 32 + lk;
#pragma unroll
            for (int mt = 0; mt < 2; ++mt)
                a[mt] = *(const bf16x8*)(src + (size_t)rows[mt] * 192 + kk);
        }
#pragma unroll
        for (int nt = 0; nt < 3; ++nt)
            b[nt] = *(const bf16x8*)(Wt + (size_t)(nb + nt * 16 + lr) * 384 + t * 32 + lk);
    };
    auto MM = [&](bf16x8 (&a)[2], bf16x8 (&b)[3]) {
#pragma unroll
        for (int mt = 0; mt < 2; ++mt)
#pragma unroll
            for (int nt = 0; nt < 3; ++nt)
                acc[mt][nt] = __builtin_amdgcn_mfma_f32_16x16x32_bf16(a[mt], b[nt], acc[mt][nt], 0, 0, 0);
    };

    LD(0, a0, b0);
#pragma unroll
    for (int t = 0; t < 12; t += 2) {
        if (t + 1 < 12) LD(t + 1, a1, b1);
        MM(a0, b0);
        if (t + 2 < 12) LD(t + 2, a0, b0);
        if (t + 1 < 12) MM(a1, b1);
    }

    int crow = lkq * 4;
#pragma unroll
    for (int mt = 0; mt < 2; ++mt)
#pragma unroll
        for (int r = 0; r < 4; ++r) {
            int orow = row0 + rbase + mt * 16 + crow + r;
            if (orow < MTOT) {
#pragma unroll
                for (int nt = 0; nt < 3; ++nt) {
                    int nn = nb + nt * 16 + lr;
                    float s = acc[mt][nt][r] + bias[nn];
                    s = fmaxf(s, 0.f);
                    if (ACT) s = 0.5f * (bf2f(hprev[(size_t)orow * 192 + nn]) + s);
                    outp[(size_t)orow * 192 + nn] = f2bf(s);
                }
            }
        }
}

// ---------------------------------------------------------------------------
// final head: block = 64 rows x 4 subs; each sub handles 48 k; quad shfl reduce
// ---------------------------------------------------------------------------
__global__ void head_a2(const ushort* __restrict__ y, const float* __restrict__ Wg,
                        const float* __restrict__ loopWg, float* __restrict__ t)
{
    int tid = threadIdx.x;
    int rloc = tid >> 2, sub = tid & 3;
    int bm = blockIdx.x * 64 + rloc;
    if (bm >= MTOT) return;
    float s[6];
#pragma unroll
    for (int c = 0; c < 6; ++c) s[c] = 0.f;
#pragma unroll
    for (int kk = 0; kk < 6; ++kk) {
        int kg = sub * 6 + kk;
        bf16x8 v = *(const bf16x8*)(y + (size_t)bm * 192 + kg * 8);
#pragma unroll
        for (int e = 0; e < 8; ++e) {
            float f = bf2f((ushort)v[e]);
            int k = kg * 8 + e;
            s[0] += f * Wg[k * 3 + 0];
            s[1] += f * Wg[k * 3 + 1];
            s[2] += f * Wg[k * 3 + 2];
            s[3] += f * loopWg[k * 3 + 0];
            s[4] += f * loopWg[k * 3 + 1];
            s[5] += f * loopWg[k * 3 + 2];
        }
    }
#pragma unroll
    for (int o = 1; o <= 2; o <<= 1)
#pragma unroll
        for (int c = 0; c < 6; ++c) s[c] += __shfl_xor(s[c], o);
    if (sub == 0) {
#pragma unroll
        for (int c = 0; c < 6; ++c) t[(size_t)bm * 6 + c] = s[c];
    }
}

__global__ void head_b(const float* __restrict__ t, const int* __restrict__ cols,
                       const float* __restrict__ vals, const float* __restrict__ bg,
                       float* __restrict__ out)
{
    int idx = blockIdx.x * 256 + threadIdx.x;
    if (idx >= MTOT * 3) return;
    int bm = idx / 3, c = idx % 3;
    int b = bm / N3V, m = bm % N3V;
    float s = 0.f;
#pragma unroll
    for (int j = 0; j < 6; ++j)
        s += vals[m * 6 + j] * t[((size_t)b * N3V + cols[m * 6 + j]) * 6 + c];
    s += t[(size_t)bm * 6 + 3 + c] + bg[c];
    out[idx] = s;
}

// ---------------------------------------------------------------------------
extern "C" void kernel_launch(void* const* d_in, const int* in_sizes, int n_in,
                              void* d_out, int out_size, void* d_ws, size_t ws_size,
                              hipStream_t stream)
{
    const float* x        = (const float*)d_in[0];
    const float* x2       = (const float*)d_in[1];
    const float* xh       = (const float*)d_in[2];
    const float* Wq       = (const float*)d_in[3];
    const float* bq       = (const float*)d_in[4];
    const float* Wk       = (const float*)d_in[5];
    const float* bk       = (const float*)d_in[6];
    const float* Wv       = (const float*)d_in[7];
    const float* bv       = (const float*)d_in[8];
    const float* adj      = (const float*)d_in[9];
    const int*   unpool   = (const int*)d_in[10];
    const float* W_in     = (const float*)d_in[11];
    const float* loopW_in = (const float*)d_in[12];
    const float* b_in     = (const float*)d_in[13];
    const float* res_W    = (const float*)d_in[14];
    const float* res_loopW= (const float*)d_in[15];
    const float* res_b    = (const float*)d_in[16];
    const float* W_out    = (const float*)d_in[17];
    const float* loopW_out= (const float*)d_in[18];
    const float* b_out    = (const float*)d_in[19];
    const float* Wg       = (const float*)d_in[20];
    const float* loopWg   = (const float*)d_in[21];
    const float* bg       = (const float*)d_in[22];
    float* out = (float*)d_out;

    char* ws = (char*)d_ws;
    size_t o = 0;
    auto alloc = [&](size_t bytes) { char* p = ws + o; o += (bytes + 255) & ~(size_t)255; return p; };
    float*  q    = (float*)alloc((size_t)M2 * 8 * 4);
    float*  kbuf = (float*)alloc((size_t)M2 * 8 * 4);
    float*  vbuf = (float*)alloc((size_t)M2 * 8 * 4);
    float*  att  = (float*)alloc((size_t)M2 * 8 * 4);
    int*    cols = (int*)alloc((size_t)N3V * 6 * 4);
    float*  vals = (float*)alloc((size_t)N3V * 6 * 4);
    int*    eidx = (int*)alloc((size_t)N3V * 12 * 4);
    float*  ewgt = (float*)alloc((size_t)N3V * 12 * 4);
    int*    sidx = (int*)alloc((size_t)N3V * 2 * 4);
    ushort* F    = (ushort*)alloc((size_t)M2 * KPAD2 * 2);
    ushort* wt_e = (ushort*)alloc((size_t)384 * KPAD2 * 2);
    ushort* wt_r = (ushort*)alloc((size_t)13 * 192 * 384 * 2);
    ushort* u2   = (ushort*)alloc((size_t)M2 * 384 * 2);
    ushort* h    = (ushort*)alloc((size_t)MTOT * 192 * 2);
    ushort* h2   = (ushort*)alloc((size_t)MTOT * 192 * 2);
    ushort* y    = (ushort*)alloc((size_t)MTOT * 192 * 2);
    float*  ts   = (float*)alloc((size_t)MTOT * 6 * 4);
    if (ws_size < o) return;

    qkv_kernel<<<(M2 + 255) / 256, 256, 0, stream>>>(x2, Wq, bq, Wk, bk, Wv, bv, q, kbuf, vbuf);
    attn_kernel2<<<dim3(NB, 10), 256, 0, stream>>>(q, kbuf, vbuf, att);
    adj_prep<<<N3V, 256, 0, stream>>>(adj, unpool, cols, vals, eidx, ewgt, sidx);
    build_F<<<M2, 256, 0, stream>>>(x, xh, att, F);
    prep_wt_all<<<ENT_TILES + RES_TILES, 256, 0, stream>>>(
        W_in, loopW_in, res_W, res_loopW, W_out, loopW_out, wt_e, wt_r);

    // entry: u2 = F @ [W_in | loopW_in]   (M=9888, K=1216, k-split x2)
    gemm_entry<<<dim3((M2 + 63) / 64, 2), 512, 0, stream>>>(F, wt_e, u2);
    combine_entry<<<(MTOT + 7) / 8, 192, 0, stream>>>(u2, eidx, ewgt, sidx, b_in, h);

    int gg = (MTOT + 63) / 64;       // 617
    ushort* cur = h;
    ushort* nxt = h2;
    for (int i = 0; i < 6; ++i) {
        const float* B0 = res_b + (size_t)(i * 2 + 0) * 192;
        const float* B1 = res_b + (size_t)(i * 2 + 1) * 192;
        const ushort* W0 = wt_r + (size_t)(i * 2 + 0) * 192 * 384;
        const ushort* W1 = wt_r + (size_t)(i * 2 + 1) * 192 * 384;
        gconv_fused<0><<<gg, 512, 0, stream>>>(cur, cols, vals, W0, B0, nullptr, y);
        gconv_fused<1><<<gg, 512, 0, stream>>>(y, cols, vals, W1, B1, cur, nxt);
        ushort* tmp = cur; cur = nxt; nxt = tmp;
    }

    // out conv (relu)
    gconv_fused<0><<<gg, 512, 0, stream>>>(cur, cols, vals,
        wt_r + (size_t)12 * 192 * 384, b_out, nullptr, y);

    head_a2<<<(MTOT + 63) / 64, 256, 0, stream>>>(y, Wg, loopWg, ts);
    head_b<<<(MTOT * 3 + 255) / 256, 256, 0, stream>>>(ts, cols, vals, bg, out);
}

// Round 13
// 440.159 us; speedup vs baseline: 1.6666x; 1.6666x over previous
//
#include <hip/hip_runtime.h>
#include <hip/hip_bf16.h>

#define NB 16
#define N2V 618
#define N3V 2466
#define FEAT 963
#define HID 192
#define IN_DIM 1163
#define KPAD2 1216         // 1163 padded to 38*32
#define ETILES 38
#define EHALF 19
#define MTOT (NB * N3V)    // 39456
#define M2   (NB * N2V)    // 9888

typedef __attribute__((ext_vector_type(8))) short bf16x8;
typedef __attribute__((ext_vector_type(4))) float f32x4;

__device__ __forceinline__ float bf2f(ushort u) {
    return __uint_as_float(((unsigned)u) << 16);
}
__device__ __forceinline__ ushort f2bf(float f) {   // round-to-nearest-even
    unsigned u = __float_as_uint(f);
    return (ushort)((u + 0x7FFFu + ((u >> 16) & 1u)) >> 16);
}
// bijective XCD-chunk swizzle (m204)
__device__ __forceinline__ int xcd_swz(int bid, int G) {
    int q = G >> 3, r = G & 7;
    int xcd = bid & 7, slot = bid >> 3;
    return (xcd < r) ? xcd * (q + 1) + slot : r * (q + 1) + (xcd - r) * q + slot;
}

// ---------------------------------------------------------------------------
// q,k,v projections: mv grade-1 only -> rows 1..3 of W
// ---------------------------------------------------------------------------
__global__ void qkv_kernel(const float* __restrict__ x2,
                           const float* __restrict__ Wq, const float* __restrict__ bq,
                           const float* __restrict__ Wk, const float* __restrict__ bk,
                           const float* __restrict__ Wv, const float* __restrict__ bv,
                           float* __restrict__ q, float* __restrict__ k, float* __restrict__ v)
{
    int idx = blockIdx.x * 256 + threadIdx.x;
    if (idx >= M2) return;
    float c0 = x2[idx * 3 + 0], c1 = x2[idx * 3 + 1], c2 = x2[idx * 3 + 2];
#pragma unroll
    for (int d = 0; d < 8; ++d) {
        q[idx * 8 + d] = bq[d] + c0 * Wq[8 + d] + c1 * Wq[16 + d] + c2 * Wq[24 + d];
        k[idx * 8 + d] = bk[d] + c0 * Wk[8 + d] + c1 * Wk[16 + d] + c2 * Wk[24 + d];
        v[idx * 8 + d] = bv[d] + c0 * Wv[8 + d] + c1 * Wv[16 + d] + c2 * Wv[24 + d];
    }
}

// ---------------------------------------------------------------------------
// attention: block = (batch, 64 queries); K,V staged in LDS (39.6KB);
// 4 lanes per query, online softmax, shfl merge across the 4 sub-lanes.
// ---------------------------------------------------------------------------
__global__ __launch_bounds__(256) void attn_kernel2(const float* __restrict__ q,
                                                    const float* __restrict__ k,
                                                    const float* __restrict__ v,
                                                    float* __restrict__ att)
{
    __shared__ float4 kv[N2V * 4];            // K: [0,2*N2V), V: [2*N2V,4*N2V)
    int b = blockIdx.x, qb = blockIdx.y;
    const float4* k4 = (const float4*)(k + (size_t)b * N2V * 8);
    const float4* v4 = (const float4*)(v + (size_t)b * N2V * 8);
    for (int i = threadIdx.x; i < N2V * 2; i += 256) {
        kv[i] = k4[i];
        kv[N2V * 2 + i] = v4[i];
    }
    __syncthreads();

    int ql = threadIdx.x >> 2, sub = threadIdx.x & 3;
    int qi = qb * 64 + ql;
    bool valid = qi < N2V;
    float qv[8];
#pragma unroll
    for (int d = 0; d < 8; ++d) qv[d] = 0.f;
    if (valid) {
#pragma unroll
        for (int d = 0; d < 8; ++d) qv[d] = q[((size_t)b * N2V + qi) * 8 + d];
    }

    const float scale = 0.35355339059327373f;
    float m = -3.0e38f, lsum = 0.f, acc[8];
#pragma unroll
    for (int d = 0; d < 8; ++d) acc[d] = 0.f;

    for (int kk = sub; kk < N2V; kk += 4) {
        float4 k0 = kv[kk * 2], k1 = kv[kk * 2 + 1];
        float s = qv[0] * k0.x + qv[1] * k0.y + qv[2] * k0.z + qv[3] * k0.w
                + qv[4] * k1.x + qv[5] * k1.y + qv[6] * k1.z + qv[7] * k1.w;
        s *= scale;
        float nm = fmaxf(m, s);
        float corr = __expf(m - nm);
        float p = __expf(s - nm);
        lsum = lsum * corr + p;
        float4 v0 = kv[N2V * 2 + kk * 2], v1 = kv[N2V * 2 + kk * 2 + 1];
        acc[0] = acc[0] * corr + p * v0.x; acc[1] = acc[1] * corr + p * v0.y;
        acc[2] = acc[2] * corr + p * v0.z; acc[3] = acc[3] * corr + p * v0.w;
        acc[4] = acc[4] * corr + p * v1.x; acc[5] = acc[5] * corr + p * v1.y;
        acc[6] = acc[6] * corr + p * v1.z; acc[7] = acc[7] * corr + p * v1.w;
        m = nm;
    }
#pragma unroll
    for (int o = 1; o <= 2; o <<= 1) {
        float m2 = __shfl_xor(m, o);
        float l2 = __shfl_xor(lsum, o);
        float nm = fmaxf(m, m2);
        float c1 = __expf(m - nm), c2 = __expf(m2 - nm);
        lsum = lsum * c1 + l2 * c2;
#pragma unroll
        for (int d = 0; d < 8; ++d) {
            float a2 = __shfl_xor(acc[d], o);
            acc[d] = acc[d] * c1 + a2 * c2;
        }
        m = nm;
    }
    if (valid && sub == 0) {
#pragma unroll
        for (int d = 0; d < 8; ++d)
            att[((size_t)b * N2V + qi) * 8 + d] = acc[d] / lsum;
    }
}

// ---------------------------------------------------------------------------
// adjacency prep: <=6 (col,val) per row (sorted), plus entry-layer expansion
// through the unpool midpoints (adj@Up, <=12 gathers) and self parent pair.
// ---------------------------------------------------------------------------
__global__ void adj_prep(const float* __restrict__ adj, const int* __restrict__ unpool,
                         int* __restrict__ cols, float* __restrict__ vals,
                         int* __restrict__ eidx, float* __restrict__ ew,
                         int* __restrict__ sidx)
{
    int m = blockIdx.x;
    __shared__ int cnt;
    __shared__ int lc[8];
    __shared__ float lv[8];
    if (threadIdx.x == 0) cnt = 0;
    __syncthreads();
    for (int c = threadIdx.x; c < N3V; c += 256) {
        float a = adj[(size_t)m * N3V + c];
        if (a != 0.f) {
            int p = atomicAdd(&cnt, 1);
            if (p < 6) { lc[p] = c; lv[p] = a; }
        }
    }
    __syncthreads();
    if (threadIdx.x == 0) {
        int n = cnt < 6 ? cnt : 6;
        for (int i = 1; i < n; ++i) {
            int ci = lc[i]; float vi = lv[i]; int j = i - 1;
            while (j >= 0 && lc[j] > ci) { lc[j + 1] = lc[j]; lv[j + 1] = lv[j]; --j; }
            lc[j + 1] = ci; lv[j + 1] = vi;
        }
        int ne = 0;
        for (int i = 0; i < 6; ++i) {
            int c = (i < n) ? lc[i] : 0;
            float w = (i < n) ? lv[i] : 0.f;
            cols[m * 6 + i] = c;
            vals[m * 6 + i] = w;
            if (i < n) {
                if (c < N2V) { eidx[m * 12 + ne] = c; ew[m * 12 + ne] = w; ++ne; }
                else {
                    int jj = c - N2V;
                    eidx[m * 12 + ne] = unpool[2 * jj];     ew[m * 12 + ne] = 0.5f * w; ++ne;
                    eidx[m * 12 + ne] = unpool[2 * jj + 1]; ew[m * 12 + ne] = 0.5f * w; ++ne;
                }
            }
        }
        for (; ne < 12; ++ne) { eidx[m * 12 + ne] = 0; ew[m * 12 + ne] = 0.f; }
        if (m < N2V) { sidx[m * 2] = m; sidx[m * 2 + 1] = -1; }
        else {
            int j = m - N2V;
            sidx[m * 2] = unpool[2 * j];
            sidx[m * 2 + 1] = unpool[2 * j + 1];
        }
    }
}

// ---------------------------------------------------------------------------
// F in FRAGMENT layout: F3[rt][kt][lane][8], row = rt*16+(lane&15),
// k = kt*32+(lane>>4)*8+j. One block per row-tile (618); writes coalesced.
// ---------------------------------------------------------------------------
__global__ void build_F3(const float* __restrict__ x, const float* __restrict__ xh,
                         const float* __restrict__ att, ushort* __restrict__ F3)
{
    int rt = blockIdx.x;                       // 0..617
    for (int c = threadIdx.x; c < ETILES * 64; c += 256) {
        int kt = c >> 6, lane = c & 63;
        int row = rt * 16 + (lane & 15);       // < M2 (618*16 = 9888)
        int k0 = kt * 32 + (lane >> 4) * 8;
        bf16x8 o;
#pragma unroll
        for (int j = 0; j < 8; ++j) {
            int k = k0 + j;
            float v = 0.f;
            if (k < FEAT) v = x[(size_t)row * FEAT + k];
            else if (k < FEAT + HID) v = xh[(size_t)row * HID + (k - FEAT)];
            else if (k < IN_DIM) v = att[(size_t)row * 8 + (k - FEAT - HID)];
            o[j] = (short)f2bf(v);
        }
        *(bf16x8*)(F3 + ((size_t)(rt * ETILES + kt) * 64 + lane) * 8) = o;
    }
}

// ---------------------------------------------------------------------------
// weight prep, FRAGMENT layout.
// entry: wt_e[ntile(24)][kt(38)][lane][8], n = ntile*16+(lane&15), k as above.
// res:   wt_r[l(13)][ntile(12)][kt(12)][lane][8], k2-fused [W k | loopW k].
// reads: lanes 0-15 hit consecutive n (one cache line); writes coalesced.
// ---------------------------------------------------------------------------
#define ENT_CHUNKS (24 * 38 * 64)
#define RES_CHUNKS (13 * 12 * 12 * 64)
__global__ void prep_wt_frag(const float* __restrict__ W_in, const float* __restrict__ loopW_in,
                             const float* __restrict__ res_W, const float* __restrict__ res_loopW,
                             const float* __restrict__ W_out, const float* __restrict__ loopW_out,
                             ushort* __restrict__ wt_e, ushort* __restrict__ wt_r)
{
    int idx = blockIdx.x * 256 + threadIdx.x;
    if (idx < ENT_CHUNKS) {
        int lane = idx & 63, r = idx >> 6;
        int kt = r % ETILES, ntile = r / ETILES;
        int n = ntile * 16 + (lane & 15);
        int k0 = kt * 32 + (lane >> 4) * 8;
        bf16x8 o;
#pragma unroll
        for (int j = 0; j < 8; ++j) {
            int k = k0 + j;
            float v = 0.f;
            if (k < IN_DIM) v = (n < 192) ? W_in[k * 192 + n] : loopW_in[k * 192 + (n - 192)];
            o[j] = (short)f2bf(v);
        }
        *(bf16x8*)(wt_e + (size_t)idx * 8) = o;
        return;
    }
    idx -= ENT_CHUNKS;
    if (idx >= RES_CHUNKS) return;
    int lane = idx & 63, r = idx >> 6;
    int kt = r % 12; r /= 12;
    int ntile = r % 12; int l = r / 12;
    const float* W = (l < 12) ? (res_W + (size_t)l * 192 * 192) : W_out;
    const float* L = (l < 12) ? (res_loopW + (size_t)l * 192 * 192) : loopW_out;
    int n = ntile * 16 + (lane & 15);
    int k0 = kt * 32 + (lane >> 4) * 8;
    bf16x8 o;
#pragma unroll
    for (int j = 0; j < 8; ++j) {
        int k2 = k0 + j;
        float v = (k2 < 192) ? W[k2 * 192 + n] : L[(k2 - 192) * 192 + n];
        o[j] = (short)f2bf(v);
    }
    *(bf16x8*)(wt_r + ((size_t)ENT_CHUNKS * 0) + ((size_t)(idx) * 8) + 0) = o;   // wt_r chunk
}

// ---------------------------------------------------------------------------
// entry GEMM, K-split x2, fragment-layout A and B (1KB coalesced wave loads).
// 512 thr (8 waves); block 64 rows x 192 cols; grid (155, 2).
// wave w: w&3 -> col group (4m x 3n), w>>2 -> k half (19 tiles each).
// High waves dump f32 partials to LDS; low waves add + store.
// ---------------------------------------------------------------------------
__global__ __launch_bounds__(512) void gemm_entry(
    const ushort* __restrict__ F3, const ushort* __restrict__ Wt,
    ushort* __restrict__ u2)
{
    __shared__ float part[64 * 192];   // 48 KB

    int tid = threadIdx.x;
    int wave = tid >> 6, lane = tid & 63;
    int kh = wave >> 2, w4 = wave & 3;
    int lr = lane & 15, lkq = lane >> 4;
    int row0 = blockIdx.x * 64;
    int rt0 = blockIdx.x * 4;
    int lnb = w4 * 48;
    int nb = blockIdx.y * 192 + lnb;
    int ntile0 = nb >> 4;
    int tbeg = kh * EHALF, tend = tbeg + EHALF;

    int rts[4];
#pragma unroll
    for (int mt = 0; mt < 4; ++mt) {
        int rt = rt0 + mt;
        rts[mt] = (rt < M2 / 16) ? rt : (M2 / 16 - 1);
    }

    f32x4 acc[4][3];
#pragma unroll
    for (int mt = 0; mt < 4; ++mt)
#pragma unroll
        for (int nt = 0; nt < 3; ++nt) acc[mt][nt] = (f32x4){0.f, 0.f, 0.f, 0.f};

    bf16x8 a0[4], b0[3], a1[4], b1[3];
    auto LD = [&](int t, bf16x8 (&a)[4], bf16x8 (&b)[3]) {
#pragma unroll
        for (int mt = 0; mt < 4; ++mt)
            a[mt] = *(const bf16x8*)(F3 + ((size_t)(rts[mt] * ETILES + t) * 64 + lane) * 8);
#pragma unroll
        for (int nt = 0; nt < 3; ++nt)
            b[nt] = *(const bf16x8*)(Wt + ((size_t)((ntile0 + nt) * ETILES + t) * 64 + lane) * 8);
    };
    auto MM = [&](bf16x8 (&a)[4], bf16x8 (&b)[3]) {
#pragma unroll
        for (int mt = 0; mt < 4; ++mt)
#pragma unroll
            for (int nt = 0; nt < 3; ++nt)
                acc[mt][nt] = __builtin_amdgcn_mfma_f32_16x16x32_bf16(a[mt], b[nt], acc[mt][nt], 0, 0, 0);
    };

    LD(tbeg, a0, b0);
    for (int t = tbeg; t < tend; t += 2) {
        if (t + 1 < tend) LD(t + 1, a1, b1);
        MM(a0, b0);
        if (t + 2 < tend) LD(t + 2, a0, b0);
        if (t + 1 < tend) MM(a1, b1);
    }

    int crow = lkq * 4;
    if (kh == 1) {
#pragma unroll
        for (int mt = 0; mt < 4; ++mt)
#pragma unroll
            for (int r = 0; r < 4; ++r)
#pragma unroll
                for (int nt = 0; nt < 3; ++nt)
                    part[(mt * 16 + crow + r) * 192 + lnb + nt * 16 + lr] = acc[mt][nt][r];
    }
    __syncthreads();
    if (kh == 0) {
#pragma unroll
        for (int mt = 0; mt < 4; ++mt)
#pragma unroll
            for (int r = 0; r < 4; ++r) {
                int orow = row0 + mt * 16 + crow + r;
                if (orow < M2) {
#pragma unroll
                    for (int nt = 0; nt < 3; ++nt) {
                        float s = acc[mt][nt][r] + part[(mt * 16 + crow + r) * 192 + lnb + nt * 16 + lr];
                        u2[(size_t)orow * 384 + nb + nt * 16 + lr] = f2bf(s);
                    }
                }
            }
    }
}

// ---------------------------------------------------------------------------
// entry combine: h = relu( sum_i ew*Pw[eidx] + mid(Pl over sidx) + bias )
// 192 thr = 8 rows x 24 col-groups of 8 (16B vector loads). XCD-swizzled.
// ---------------------------------------------------------------------------
__global__ void combine_entry(const ushort* __restrict__ u2, const int* __restrict__ eidx,
                              const float* __restrict__ ew, const int* __restrict__ sidx,
                              const float* __restrict__ bias, ushort* __restrict__ h)
{
    int lb = xcd_swz(blockIdx.x, gridDim.x);
    int tid = threadIdx.x;
    int rloc = tid / 24, f8 = tid % 24;
    int bm = lb * 8 + rloc;
    if (bm >= MTOT) return;
    int b = bm / N3V, n = bm % N3V;
    const ushort* base = u2 + (size_t)b * N2V * 384;

    float acc[8];
#pragma unroll
    for (int e = 0; e < 8; ++e) acc[e] = 0.f;
#pragma unroll
    for (int i = 0; i < 12; ++i) {
        float w = ew[n * 12 + i];
        bf16x8 v = *(const bf16x8*)(base + (size_t)eidx[n * 12 + i] * 384 + f8 * 8);
#pragma unroll
        for (int e = 0; e < 8; ++e) acc[e] += w * bf2f((ushort)v[e]);
    }
    int p0 = sidx[n * 2], p1 = sidx[n * 2 + 1];
    bf16x8 s0 = *(const bf16x8*)(base + (size_t)p0 * 384 + 192 + f8 * 8);
    if (p1 >= 0) {
        bf16x8 s1 = *(const bf16x8*)(base + (size_t)p1 * 384 + 192 + f8 * 8);
#pragma unroll
        for (int e = 0; e < 8; ++e) acc[e] += 0.5f * (bf2f((ushort)s0[e]) + bf2f((ushort)s1[e]));
    } else {
#pragma unroll
        for (int e = 0; e < 8; ++e) acc[e] += bf2f((ushort)s0[e]);
    }
    bf16x8 o;
#pragma unroll
    for (int e = 0; e < 8; ++e)
        o[e] = (short)f2bf(fmaxf(acc[e] + bias[f8 * 8 + e], 0.f));
    *(bf16x8*)(h + (size_t)bm * 192 + f8 * 8) = o;
}

// ---------------------------------------------------------------------------
// fused res GConv (r11 structure): out = act( [adj@src | src] @ Wt^T + bias )
// 512 thr, 32-row block, grid 1233 (XCD-swizzled).
// Phase 0: 768 gather tasks (1.5/thread) -> g staged in 12KB XOR-swizzled LDS.
// Phase 1: K-split GEMM: waves 0-3 A=LDS(g), waves 4-7 A=src rows (L2);
//          B from fragment-layout wt_r (coalesced); f32 reduce in 24KB LDS.
// ACT 0: relu; ACT 1: 0.5*(hprev + relu(.)).
// ---------------------------------------------------------------------------
template <int ACT>
__global__ __launch_bounds__(512) void gconv_fused(
    const ushort* __restrict__ src, const int* __restrict__ cols,
    const float* __restrict__ vals, const ushort* __restrict__ Wt,
    const float* __restrict__ bias, const ushort* __restrict__ hprev,
    ushort* __restrict__ outp)
{
    __shared__ ushort gs[32 * 192];    // 12 KB, XOR-swizzled
    __shared__ float part[32 * 192];   // 24 KB

    int lb = xcd_swz(blockIdx.x, gridDim.x);
    int tid = threadIdx.x;
    int row0 = lb * 32;                // MTOT % 32 == 0

    // ---- phase 0: g = adj @ src for this block's 32 rows -> LDS ----
    for (int task = tid; task < 768; task += 512) {
        int r = task / 24, f8 = task % 24;
        int bm = row0 + r;
        int b = bm / N3V, m = bm % N3V;
        const ushort* hb = src + (size_t)b * N3V * 192;
        float acc[8];
#pragma unroll
        for (int e = 0; e < 8; ++e) acc[e] = 0.f;
#pragma unroll
        for (int j = 0; j < 6; ++j) {
            float w = vals[m * 6 + j];
            bf16x8 v = *(const bf16x8*)(hb + (size_t)cols[m * 6 + j] * 192 + f8 * 8);
#pragma unroll
            for (int e = 0; e < 8; ++e) acc[e] += w * bf2f((ushort)v[e]);
        }
        bf16x8 o;
#pragma unroll
        for (int e = 0; e < 8; ++e) o[e] = (short)f2bf(acc[e]);
        int byte = r * 384 + f8 * 16;
        byte ^= (r & 7) << 4;
        *(bf16x8*)((char*)gs + byte) = o;
    }
    __syncthreads();

    // ---- phase 1: K-split GEMM ----
    int wave = tid >> 6, lane = tid & 63;
    int kh = wave >> 2, w4 = wave & 3;
    int lr = lane & 15, lkq = lane >> 4, lk = lkq * 8;
    int nb = w4 * 48;
    int ntile0 = nb >> 4;
    int rows[2] = { row0 + lr, row0 + 16 + lr };
    int ktb = kh * 6;                  // fragment k-tile base for this half

    f32x4 acc[2][3];
#pragma unroll
    for (int mt = 0; mt < 2; ++mt)
#pragma unroll
        for (int nt = 0; nt < 3; ++nt) acc[mt][nt] = (f32x4){0.f, 0.f, 0.f, 0.f};

    bf16x8 a0[2], b0[3], a1[2], b1[3];
    auto LD = [&](int t, bf16x8 (&a)[2], bf16x8 (&b)[3]) {
        if (kh == 0) {
#pragma unroll
            for (int mt = 0; mt < 2; ++mt) {
                int rr = mt * 16 + lr;
                int byte = rr * 384 + t * 64 + lkq * 16;
                byte ^= (rr & 7) << 4;
                a[mt] = *(const bf16x8*)((const char*)gs + byte);
            }
        } else {
            int kk = t * 32 + lk;
#pragma unroll
            for (int mt = 0; mt < 2; ++mt)
                a[mt] = *(const bf16x8*)(src + (size_t)rows[mt] * 192 + kk);
        }
#pragma unroll
        for (int nt = 0; nt < 3; ++nt)
            b[nt] = *(const bf16x8*)(Wt + ((size_t)((ntile0 + nt) * 12 + ktb + t) * 64 + lane) * 8);
    };
    auto MM = [&](bf16x8 (&a)[2], bf16x8 (&b)[3]) {
#pragma unroll
        for (int mt = 0; mt < 2; ++mt)
#pragma unroll
            for (int nt = 0; nt < 3; ++nt)
                acc[mt][nt] = __builtin_amdgcn_mfma_f32_16x16x32_bf16(a[mt], b[nt], acc[mt][nt], 0, 0, 0);
    };

    LD(0, a0, b0);
#pragma unroll
    for (int t = 0; t < 6; t += 2) {
        if (t + 1 < 6) LD(t + 1, a1, b1);
        MM(a0, b0);
        if (t + 2 < 6) LD(t + 2, a0, b0);
        if (t + 1 < 6) MM(a1, b1);
    }

    int crow = lkq * 4;
    if (kh == 1) {
#pragma unroll
        for (int mt = 0; mt < 2; ++mt)
#pragma unroll
            for (int r = 0; r < 4; ++r)
#pragma unroll
                for (int nt = 0; nt < 3; ++nt)
                    part[(mt * 16 + crow + r) * 192 + nb + nt * 16 + lr] = acc[mt][nt][r];
    }
    __syncthreads();
    if (kh == 0) {
#pragma unroll
        for (int mt = 0; mt < 2; ++mt)
#pragma unroll
            for (int r = 0; r < 4; ++r) {
                int orow = row0 + mt * 16 + crow + r;
#pragma unroll
                for (int nt = 0; nt < 3; ++nt) {
                    int nn = nb + nt * 16 + lr;
                    float s = acc[mt][nt][r] + part[(mt * 16 + crow + r) * 192 + nn] + bias[nn];
                    s = fmaxf(s, 0.f);
                    if (ACT) s = 0.5f * (bf2f(hprev[(size_t)orow * 192 + nn]) + s);
                    outp[(size_t)orow * 192 + nn] = f2bf(s);
                }
            }
    }
}

// ---------------------------------------------------------------------------
// final head: block = 64 rows x 4 subs; each sub handles 48 k; quad shfl reduce
// ---------------------------------------------------------------------------
__global__ void head_a2(const ushort* __restrict__ y, const float* __restrict__ Wg,
                        const float* __restrict__ loopWg, float* __restrict__ t)
{
    int tid = threadIdx.x;
    int rloc = tid >> 2, sub = tid & 3;
    int bm = blockIdx.x * 64 + rloc;
    if (bm >= MTOT) return;
    float s[6];
#pragma unroll
    for (int c = 0; c < 6; ++c) s[c] = 0.f;
#pragma unroll
    for (int kk = 0; kk < 6; ++kk) {
        int kg = sub * 6 + kk;
        bf16x8 v = *(const bf16x8*)(y + (size_t)bm * 192 + kg * 8);
#pragma unroll
        for (int e = 0; e < 8; ++e) {
            float f = bf2f((ushort)v[e]);
            int k = kg * 8 + e;
            s[0] += f * Wg[k * 3 + 0];
            s[1] += f * Wg[k * 3 + 1];
            s[2] += f * Wg[k * 3 + 2];
            s[3] += f * loopWg[k * 3 + 0];
            s[4] += f * loopWg[k * 3 + 1];
            s[5] += f * loopWg[k * 3 + 2];
        }
    }
#pragma unroll
    for (int o = 1; o <= 2; o <<= 1)
#pragma unroll
        for (int c = 0; c < 6; ++c) s[c] += __shfl_xor(s[c], o);
    if (sub == 0) {
#pragma unroll
        for (int c = 0; c < 6; ++c) t[(size_t)bm * 6 + c] = s[c];
    }
}

__global__ void head_b(const float* __restrict__ t, const int* __restrict__ cols,
                       const float* __restrict__ vals, const float* __restrict__ bg,
                       float* __restrict__ out)
{
    int idx = blockIdx.x * 256 + threadIdx.x;
    if (idx >= MTOT * 3) return;
    int bm = idx / 3, c = idx % 3;
    int b = bm / N3V, m = bm % N3V;
    float s = 0.f;
#pragma unroll
    for (int j = 0; j < 6; ++j)
        s += vals[m * 6 + j] * t[((size_t)b * N3V + cols[m * 6 + j]) * 6 + c];
    s += t[(size_t)bm * 6 + 3 + c] + bg[c];
    out[idx] = s;
}

// ---------------------------------------------------------------------------
extern "C" void kernel_launch(void* const* d_in, const int* in_sizes, int n_in,
                              void* d_out, int out_size, void* d_ws, size_t ws_size,
                              hipStream_t stream)
{
    const float* x        = (const float*)d_in[0];
    const float* x2       = (const float*)d_in[1];
    const float* xh       = (const float*)d_in[2];
    const float* Wq       = (const float*)d_in[3];
    const float* bq       = (const float*)d_in[4];
    const float* Wk       = (const float*)d_in[5];
    const float* bk       = (const float*)d_in[6];
    const float* Wv       = (const float*)d_in[7];
    const float* bv       = (const float*)d_in[8];
    const float* adj      = (const float*)d_in[9];
    const int*   unpool   = (const int*)d_in[10];
    const float* W_in     = (const float*)d_in[11];
    const float* loopW_in = (const float*)d_in[12];
    const float* b_in     = (const float*)d_in[13];
    const float* res_W    = (const float*)d_in[14];
    const float* res_loopW= (const float*)d_in[15];
    const float* res_b    = (const float*)d_in[16];
    const float* W_out    = (const float*)d_in[17];
    const float* loopW_out= (const float*)d_in[18];
    const float* b_out    = (const float*)d_in[19];
    const float* Wg       = (const float*)d_in[20];
    const float* loopWg   = (const float*)d_in[21];
    const float* bg       = (const float*)d_in[22];
    float* out = (float*)d_out;

    char* ws = (char*)d_ws;
    size_t o = 0;
    auto alloc = [&](size_t bytes) { char* p = ws + o; o += (bytes + 255) & ~(size_t)255; return p; };
    float*  q    = (float*)alloc((size_t)M2 * 8 * 4);
    float*  kbuf = (float*)alloc((size_t)M2 * 8 * 4);
    float*  vbuf = (float*)alloc((size_t)M2 * 8 * 4);
    float*  att  = (float*)alloc((size_t)M2 * 8 * 4);
    int*    cols = (int*)alloc((size_t)N3V * 6 * 4);
    float*  vals = (float*)alloc((size_t)N3V * 6 * 4);
    int*    eidx = (int*)alloc((size_t)N3V * 12 * 4);
    float*  ewgt = (float*)alloc((size_t)N3V * 12 * 4);
    int*    sidx = (int*)alloc((size_t)N3V * 2 * 4);
    ushort* F3   = (ushort*)alloc((size_t)M2 * KPAD2 * 2);
    ushort* wt_e = (ushort*)alloc((size_t)ENT_CHUNKS * 8 * 2);
    ushort* wt_r = (ushort*)alloc((size_t)RES_CHUNKS * 8 * 2);
    ushort* u2   = (ushort*)alloc((size_t)M2 * 384 * 2);
    ushort* h    = (ushort*)alloc((size_t)MTOT * 192 * 2);
    ushort* h2   = (ushort*)alloc((size_t)MTOT * 192 * 2);
    ushort* y    = (ushort*)alloc((size_t)MTOT * 192 * 2);
    float*  ts   = (float*)alloc((size_t)MTOT * 6 * 4);
    if (ws_size < o) return;

    qkv_kernel<<<(M2 + 255) / 256, 256, 0, stream>>>(x2, Wq, bq, Wk, bk, Wv, bv, q, kbuf, vbuf);
    attn_kernel2<<<dim3(NB, 10), 256, 0, stream>>>(q, kbuf, vbuf, att);
    adj_prep<<<N3V, 256, 0, stream>>>(adj, unpool, cols, vals, eidx, ewgt, sidx);
    build_F3<<<M2 / 16, 256, 0, stream>>>(x, xh, att, F3);
    prep_wt_frag<<<(ENT_CHUNKS + RES_CHUNKS + 255) / 256, 256, 0, stream>>>(
        W_in, loopW_in, res_W, res_loopW, W_out, loopW_out, wt_e, wt_r);

    // entry: u2 = F @ [W_in | loopW_in]   (M=9888, K=1216, k-split x2)
    gemm_entry<<<dim3((M2 + 63) / 64, 2), 512, 0, stream>>>(F3, wt_e, u2);
    combine_entry<<<(MTOT + 7) / 8, 192, 0, stream>>>(u2, eidx, ewgt, sidx, b_in, h);

    int gg = MTOT / 32;              // 1233
    ushort* cur = h;
    ushort* nxt = h2;
    for (int i = 0; i < 6; ++i) {
        const float* B0 = res_b + (size_t)(i * 2 + 0) * 192;
        const float* B1 = res_b + (size_t)(i * 2 + 1) * 192;
        const ushort* W0 = wt_r + (size_t)(i * 2 + 0) * (12 * 12 * 64 * 8);
        const ushort* W1 = wt_r + (size_t)(i * 2 + 1) * (12 * 12 * 64 * 8);
        gconv_fused<0><<<gg, 512, 0, stream>>>(cur, cols, vals, W0, B0, nullptr, y);
        gconv_fused<1><<<gg, 512, 0, stream>>>(y, cols, vals, W1, B1, cur, nxt);
        ushort* tmp = cur; cur = nxt; nxt = tmp;
    }

    // out conv (relu)
    gconv_fused<0><<<gg, 512, 0, stream>>>(cur, cols, vals,
        wt_r + (size_t)12 * (12 * 12 * 64 * 8), b_out, nullptr, y);

    head_a2<<<(MTOT + 63) / 64, 256, 0, stream>>>(y, Wg, loopWg, ts);
    head_b<<<(MTOT * 3 + 255) / 256, 256, 0, stream>>>(ts, cols, vals, bg, out);
}

// Round 14
// 426.004 us; speedup vs baseline: 1.7219x; 1.0332x over previous
//
#include <hip/hip_runtime.h>
#include <hip/hip_bf16.h>

#define NB 16
#define N2V 618
#define N3V 2466
#define FEAT 963
#define HID 192
#define IN_DIM 1163
#define KPAD2 1216         // 1163 padded to 38*32
#define ETILES 38
#define EHALF 19
#define MTOT (NB * N3V)    // 39456
#define M2   (NB * N2V)    // 9888

typedef __attribute__((ext_vector_type(8))) short bf16x8;
typedef __attribute__((ext_vector_type(4))) float f32x4;

__device__ __forceinline__ float bf2f(ushort u) {
    return __uint_as_float(((unsigned)u) << 16);
}
__device__ __forceinline__ ushort f2bf(float f) {   // round-to-nearest-even
    unsigned u = __float_as_uint(f);
    return (ushort)((u + 0x7FFFu + ((u >> 16) & 1u)) >> 16);
}
// bijective XCD-chunk swizzle (m204)
__device__ __forceinline__ int xcd_swz(int bid, int G) {
    int q = G >> 3, r = G & 7;
    int xcd = bid & 7, slot = bid >> 3;
    return (xcd < r) ? xcd * (q + 1) + slot : r * (q + 1) + (xcd - r) * q + slot;
}

// ---------------------------------------------------------------------------
// fused qkv + attention: block = (batch, 64 queries).
// K,V computed from x2 directly into LDS (mv grade-1 -> rows 1..3 of W).
// 4 lanes per query, online softmax, shfl merge across the 4 sub-lanes.
// ---------------------------------------------------------------------------
__global__ __launch_bounds__(256) void attn_fused(
    const float* __restrict__ x2,
    const float* __restrict__ Wq, const float* __restrict__ bq,
    const float* __restrict__ Wk, const float* __restrict__ bk,
    const float* __restrict__ Wv, const float* __restrict__ bv,
    float* __restrict__ att)
{
    __shared__ float4 kv[N2V * 4];            // K: [0,2*N2V), V: [2*N2V,4*N2V)
    int b = blockIdx.x, qb = blockIdx.y;
    const float* x2b = x2 + (size_t)b * N2V * 3;

    for (int i = threadIdx.x; i < N2V; i += 256) {
        float c0 = x2b[i * 3], c1 = x2b[i * 3 + 1], c2 = x2b[i * 3 + 2];
        float kk[8], vv[8];
#pragma unroll
        for (int d = 0; d < 8; ++d) {
            kk[d] = bk[d] + c0 * Wk[8 + d] + c1 * Wk[16 + d] + c2 * Wk[24 + d];
            vv[d] = bv[d] + c0 * Wv[8 + d] + c1 * Wv[16 + d] + c2 * Wv[24 + d];
        }
        kv[i * 2]     = (float4){kk[0], kk[1], kk[2], kk[3]};
        kv[i * 2 + 1] = (float4){kk[4], kk[5], kk[6], kk[7]};
        kv[N2V * 2 + i * 2]     = (float4){vv[0], vv[1], vv[2], vv[3]};
        kv[N2V * 2 + i * 2 + 1] = (float4){vv[4], vv[5], vv[6], vv[7]};
    }
    __syncthreads();

    int ql = threadIdx.x >> 2, sub = threadIdx.x & 3;
    int qi = qb * 64 + ql;
    bool valid = qi < N2V;
    float qv[8];
#pragma unroll
    for (int d = 0; d < 8; ++d) qv[d] = 0.f;
    if (valid) {
        float c0 = x2b[qi * 3], c1 = x2b[qi * 3 + 1], c2 = x2b[qi * 3 + 2];
#pragma unroll
        for (int d = 0; d < 8; ++d)
            qv[d] = bq[d] + c0 * Wq[8 + d] + c1 * Wq[16 + d] + c2 * Wq[24 + d];
    }

    const float scale = 0.35355339059327373f;
    float m = -3.0e38f, lsum = 0.f, acc[8];
#pragma unroll
    for (int d = 0; d < 8; ++d) acc[d] = 0.f;

    for (int kk = sub; kk < N2V; kk += 4) {
        float4 k0 = kv[kk * 2], k1 = kv[kk * 2 + 1];
        float s = qv[0] * k0.x + qv[1] * k0.y + qv[2] * k0.z + qv[3] * k0.w
                + qv[4] * k1.x + qv[5] * k1.y + qv[6] * k1.z + qv[7] * k1.w;
        s *= scale;
        float nm = fmaxf(m, s);
        float corr = __expf(m - nm);
        float p = __expf(s - nm);
        lsum = lsum * corr + p;
        float4 v0 = kv[N2V * 2 + kk * 2], v1 = kv[N2V * 2 + kk * 2 + 1];
        acc[0] = acc[0] * corr + p * v0.x; acc[1] = acc[1] * corr + p * v0.y;
        acc[2] = acc[2] * corr + p * v0.z; acc[3] = acc[3] * corr + p * v0.w;
        acc[4] = acc[4] * corr + p * v1.x; acc[5] = acc[5] * corr + p * v1.y;
        acc[6] = acc[6] * corr + p * v1.z; acc[7] = acc[7] * corr + p * v1.w;
        m = nm;
    }
#pragma unroll
    for (int o = 1; o <= 2; o <<= 1) {
        float m2 = __shfl_xor(m, o);
        float l2 = __shfl_xor(lsum, o);
        float nm = fmaxf(m, m2);
        float c1 = __expf(m - nm), c2 = __expf(m2 - nm);
        lsum = lsum * c1 + l2 * c2;
#pragma unroll
        for (int d = 0; d < 8; ++d) {
            float a2 = __shfl_xor(acc[d], o);
            acc[d] = acc[d] * c1 + a2 * c2;
        }
        m = nm;
    }
    if (valid && sub == 0) {
#pragma unroll
        for (int d = 0; d < 8; ++d)
            att[((size_t)b * N2V + qi) * 8 + d] = acc[d] / lsum;
    }
}

// ---------------------------------------------------------------------------
// adjacency prep: <=6 (col,val) per row (sorted), plus entry-layer expansion
// through the unpool midpoints (adj@Up, <=12 gathers) and self parent pair.
// ---------------------------------------------------------------------------
__global__ void adj_prep(const float* __restrict__ adj, const int* __restrict__ unpool,
                         int* __restrict__ cols, float* __restrict__ vals,
                         int* __restrict__ eidx, float* __restrict__ ew,
                         int* __restrict__ sidx)
{
    int m = blockIdx.x;
    __shared__ int cnt;
    __shared__ int lc[8];
    __shared__ float lv[8];
    if (threadIdx.x == 0) cnt = 0;
    __syncthreads();
    for (int c = threadIdx.x; c < N3V; c += 256) {
        float a = adj[(size_t)m * N3V + c];
        if (a != 0.f) {
            int p = atomicAdd(&cnt, 1);
            if (p < 6) { lc[p] = c; lv[p] = a; }
        }
    }
    __syncthreads();
    if (threadIdx.x == 0) {
        int n = cnt < 6 ? cnt : 6;
        for (int i = 1; i < n; ++i) {
            int ci = lc[i]; float vi = lv[i]; int j = i - 1;
            while (j >= 0 && lc[j] > ci) { lc[j + 1] = lc[j]; lv[j + 1] = lv[j]; --j; }
            lc[j + 1] = ci; lv[j + 1] = vi;
        }
        int ne = 0;
        for (int i = 0; i < 6; ++i) {
            int c = (i < n) ? lc[i] : 0;
            float w = (i < n) ? lv[i] : 0.f;
            cols[m * 6 + i] = c;
            vals[m * 6 + i] = w;
            if (i < n) {
                if (c < N2V) { eidx[m * 12 + ne] = c; ew[m * 12 + ne] = w; ++ne; }
                else {
                    int jj = c - N2V;
                    eidx[m * 12 + ne] = unpool[2 * jj];     ew[m * 12 + ne] = 0.5f * w; ++ne;
                    eidx[m * 12 + ne] = unpool[2 * jj + 1]; ew[m * 12 + ne] = 0.5f * w; ++ne;
                }
            }
        }
        for (; ne < 12; ++ne) { eidx[m * 12 + ne] = 0; ew[m * 12 + ne] = 0.f; }
        if (m < N2V) { sidx[m * 2] = m; sidx[m * 2 + 1] = -1; }
        else {
            int j = m - N2V;
            sidx[m * 2] = unpool[2 * j];
            sidx[m * 2 + 1] = unpool[2 * j + 1];
        }
    }
}

// ---------------------------------------------------------------------------
// F in FRAGMENT layout: F3[rt][kt][lane][8], row = rt*16+(lane&15),
// k = kt*32+(lane>>4)*8+j. One block per row-tile (618); writes coalesced.
// ---------------------------------------------------------------------------
__global__ void build_F3(const float* __restrict__ x, const float* __restrict__ xh,
                         const float* __restrict__ att, ushort* __restrict__ F3)
{
    int rt = blockIdx.x;                       // 0..617
    for (int c = threadIdx.x; c < ETILES * 64; c += 256) {
        int kt = c >> 6, lane = c & 63;
        int row = rt * 16 + (lane & 15);       // < M2
        int k0 = kt * 32 + (lane >> 4) * 8;
        bf16x8 o;
#pragma unroll
        for (int j = 0; j < 8; ++j) {
            int k = k0 + j;
            float v = 0.f;
            if (k < FEAT) v = x[(size_t)row * FEAT + k];
            else if (k < FEAT + HID) v = xh[(size_t)row * HID + (k - FEAT)];
            else if (k < IN_DIM) v = att[(size_t)row * 8 + (k - FEAT - HID)];
            o[j] = (short)f2bf(v);
        }
        *(bf16x8*)(F3 + ((size_t)(rt * ETILES + kt) * 64 + lane) * 8) = o;
    }
}

// ---------------------------------------------------------------------------
// weight prep, FRAGMENT layout.
// entry: wt_e[ntile(24)][kt(38)][lane][8]; res: wt_r[l][ntile(12)][kt(12)][lane][8]
// ---------------------------------------------------------------------------
#define ENT_CHUNKS (24 * 38 * 64)
#define RES_CHUNKS (13 * 12 * 12 * 64)
__global__ void prep_wt_frag(const float* __restrict__ W_in, const float* __restrict__ loopW_in,
                             const float* __restrict__ res_W, const float* __restrict__ res_loopW,
                             const float* __restrict__ W_out, const float* __restrict__ loopW_out,
                             ushort* __restrict__ wt_e, ushort* __restrict__ wt_r)
{
    int idx = blockIdx.x * 256 + threadIdx.x;
    if (idx < ENT_CHUNKS) {
        int lane = idx & 63, r = idx >> 6;
        int kt = r % ETILES, ntile = r / ETILES;
        int n = ntile * 16 + (lane & 15);
        int k0 = kt * 32 + (lane >> 4) * 8;
        bf16x8 o;
#pragma unroll
        for (int j = 0; j < 8; ++j) {
            int k = k0 + j;
            float v = 0.f;
            if (k < IN_DIM) v = (n < 192) ? W_in[k * 192 + n] : loopW_in[k * 192 + (n - 192)];
            o[j] = (short)f2bf(v);
        }
        *(bf16x8*)(wt_e + (size_t)idx * 8) = o;
        return;
    }
    idx -= ENT_CHUNKS;
    if (idx >= RES_CHUNKS) return;
    int lane = idx & 63, r = idx >> 6;
    int kt = r % 12; r /= 12;
    int ntile = r % 12; int l = r / 12;
    const float* W = (l < 12) ? (res_W + (size_t)l * 192 * 192) : W_out;
    const float* L = (l < 12) ? (res_loopW + (size_t)l * 192 * 192) : loopW_out;
    int n = ntile * 16 + (lane & 15);
    int k0 = kt * 32 + (lane >> 4) * 8;
    bf16x8 o;
#pragma unroll
    for (int j = 0; j < 8; ++j) {
        int k2 = k0 + j;
        float v = (k2 < 192) ? W[k2 * 192 + n] : L[(k2 - 192) * 192 + n];
        o[j] = (short)f2bf(v);
    }
    *(bf16x8*)(wt_r + (size_t)idx * 8) = o;
}

// ---------------------------------------------------------------------------
// entry GEMM, K-split x2, fragment-layout A and B (1KB coalesced wave loads).
// 512 thr (8 waves); block 64 rows x 192 cols; grid (155, 2).
// ---------------------------------------------------------------------------
__global__ __launch_bounds__(512) void gemm_entry(
    const ushort* __restrict__ F3, const ushort* __restrict__ Wt,
    ushort* __restrict__ u2)
{
    __shared__ float part[64 * 192];   // 48 KB

    int tid = threadIdx.x;
    int wave = tid >> 6, lane = tid & 63;
    int kh = wave >> 2, w4 = wave & 3;
    int lr = lane & 15, lkq = lane >> 4;
    int row0 = blockIdx.x * 64;
    int rt0 = blockIdx.x * 4;
    int lnb = w4 * 48;
    int nb = blockIdx.y * 192 + lnb;
    int ntile0 = nb >> 4;
    int tbeg = kh * EHALF, tend = tbeg + EHALF;

    int rts[4];
#pragma unroll
    for (int mt = 0; mt < 4; ++mt) {
        int rt = rt0 + mt;
        rts[mt] = (rt < M2 / 16) ? rt : (M2 / 16 - 1);
    }

    f32x4 acc[4][3];
#pragma unroll
    for (int mt = 0; mt < 4; ++mt)
#pragma unroll
        for (int nt = 0; nt < 3; ++nt) acc[mt][nt] = (f32x4){0.f, 0.f, 0.f, 0.f};

    bf16x8 a0[4], b0[3], a1[4], b1[3];
    auto LD = [&](int t, bf16x8 (&a)[4], bf16x8 (&b)[3]) {
#pragma unroll
        for (int mt = 0; mt < 4; ++mt)
            a[mt] = *(const bf16x8*)(F3 + ((size_t)(rts[mt] * ETILES + t) * 64 + lane) * 8);
#pragma unroll
        for (int nt = 0; nt < 3; ++nt)
            b[nt] = *(const bf16x8*)(Wt + ((size_t)((ntile0 + nt) * ETILES + t) * 64 + lane) * 8);
    };
    auto MM = [&](bf16x8 (&a)[4], bf16x8 (&b)[3]) {
#pragma unroll
        for (int mt = 0; mt < 4; ++mt)
#pragma unroll
            for (int nt = 0; nt < 3; ++nt)
                acc[mt][nt] = __builtin_amdgcn_mfma_f32_16x16x32_bf16(a[mt], b[nt], acc[mt][nt], 0, 0, 0);
    };

    LD(tbeg, a0, b0);
    for (int t = tbeg; t < tend; t += 2) {
        if (t + 1 < tend) LD(t + 1, a1, b1);
        MM(a0, b0);
        if (t + 2 < tend) LD(t + 2, a0, b0);
        if (t + 1 < tend) MM(a1, b1);
    }

    int crow = lkq * 4;
    if (kh == 1) {
#pragma unroll
        for (int mt = 0; mt < 4; ++mt)
#pragma unroll
            for (int r = 0; r < 4; ++r)
#pragma unroll
                for (int nt = 0; nt < 3; ++nt)
                    part[(mt * 16 + crow + r) * 192 + lnb + nt * 16 + lr] = acc[mt][nt][r];
    }
    __syncthreads();
    if (kh == 0) {
#pragma unroll
        for (int mt = 0; mt < 4; ++mt)
#pragma unroll
            for (int r = 0; r < 4; ++r) {
                int orow = row0 + mt * 16 + crow + r;
                if (orow < M2) {
#pragma unroll
                    for (int nt = 0; nt < 3; ++nt) {
                        float s = acc[mt][nt][r] + part[(mt * 16 + crow + r) * 192 + lnb + nt * 16 + lr];
                        u2[(size_t)orow * 384 + nb + nt * 16 + lr] = f2bf(s);
                    }
                }
            }
    }
}

// ---------------------------------------------------------------------------
// entry combine: h = relu( sum_i ew*Pw[eidx] + mid(Pl over sidx) + bias )
// ---------------------------------------------------------------------------
__global__ void combine_entry(const ushort* __restrict__ u2, const int* __restrict__ eidx,
                              const float* __restrict__ ew, const int* __restrict__ sidx,
                              const float* __restrict__ bias, ushort* __restrict__ h)
{
    int lb = xcd_swz(blockIdx.x, gridDim.x);
    int tid = threadIdx.x;
    int rloc = tid / 24, f8 = tid % 24;
    int bm = lb * 8 + rloc;
    if (bm >= MTOT) return;
    int b = bm / N3V, n = bm % N3V;
    const ushort* base = u2 + (size_t)b * N2V * 384;

    float acc[8];
#pragma unroll
    for (int e = 0; e < 8; ++e) acc[e] = 0.f;
#pragma unroll
    for (int i = 0; i < 12; ++i) {
        float w = ew[n * 12 + i];
        bf16x8 v = *(const bf16x8*)(base + (size_t)eidx[n * 12 + i] * 384 + f8 * 8);
#pragma unroll
        for (int e = 0; e < 8; ++e) acc[e] += w * bf2f((ushort)v[e]);
    }
    int p0 = sidx[n * 2], p1 = sidx[n * 2 + 1];
    bf16x8 s0 = *(const bf16x8*)(base + (size_t)p0 * 384 + 192 + f8 * 8);
    if (p1 >= 0) {
        bf16x8 s1 = *(const bf16x8*)(base + (size_t)p1 * 384 + 192 + f8 * 8);
#pragma unroll
        for (int e = 0; e < 8; ++e) acc[e] += 0.5f * (bf2f((ushort)s0[e]) + bf2f((ushort)s1[e]));
    } else {
#pragma unroll
        for (int e = 0; e < 8; ++e) acc[e] += bf2f((ushort)s0[e]);
    }
    bf16x8 o;
#pragma unroll
    for (int e = 0; e < 8; ++e)
        o[e] = (short)f2bf(fmaxf(acc[e] + bias[f8 * 8 + e], 0.f));
    *(bf16x8*)(h + (size_t)bm * 192 + f8 * 8) = o;
}

// ---------------------------------------------------------------------------
// fused res GConv, WAVE-SPECIALIZED, single barrier:
//   waves 4-7 (kh=1): run self-half GEMM immediately (no gs dependency),
//                     dump f32 partials to LDS, hit barrier.
//   waves 0-3 (kh=0): gather 768 tasks (3/thread over 256 thr) -> gs
//                     (XOR-swizzled), hit barrier, then g-half GEMM from LDS,
//                     add partials + bias (+residual), store.
// Gather latency hides under the other half's MFMA stream. 512 thr, 32-row
// block, grid 1233 (XCD-swizzled). B from fragment-layout wt_r.
// ---------------------------------------------------------------------------
template <int ACT>
__global__ __launch_bounds__(512) void gconv_fused(
    const ushort* __restrict__ src, const int* __restrict__ cols,
    const float* __restrict__ vals, const ushort* __restrict__ Wt,
    const float* __restrict__ bias, const ushort* __restrict__ hprev,
    ushort* __restrict__ outp)
{
    __shared__ ushort gs[32 * 192];    // 12 KB, XOR-swizzled
    __shared__ float part[32 * 192];   // 24 KB

    int lb = xcd_swz(blockIdx.x, gridDim.x);
    int tid = threadIdx.x;
    int row0 = lb * 32;                // MTOT % 32 == 0

    int wave = tid >> 6, lane = tid & 63;
    int kh = wave >> 2, w4 = wave & 3;
    int lr = lane & 15, lkq = lane >> 4, lk = lkq * 8;
    int nb = w4 * 48;
    int ntile0 = nb >> 4;
    int rows[2] = { row0 + lr, row0 + 16 + lr };
    int ktb = kh * 6;

    f32x4 acc[2][3];
#pragma unroll
    for (int mt = 0; mt < 2; ++mt)
#pragma unroll
        for (int nt = 0; nt < 3; ++nt) acc[mt][nt] = (f32x4){0.f, 0.f, 0.f, 0.f};

    bf16x8 a0[2], b0[3], a1[2], b1[3];
    auto LDself = [&](int t, bf16x8 (&a)[2], bf16x8 (&b)[3]) {
        int kk = t * 32 + lk;
#pragma unroll
        for (int mt = 0; mt < 2; ++mt)
            a[mt] = *(const bf16x8*)(src + (size_t)rows[mt] * 192 + kk);
#pragma unroll
        for (int nt = 0; nt < 3; ++nt)
            b[nt] = *(const bf16x8*)(Wt + ((size_t)((ntile0 + nt) * 12 + ktb + t) * 64 + lane) * 8);
    };
    auto LDg = [&](int t, bf16x8 (&a)[2], bf16x8 (&b)[3]) {
#pragma unroll
        for (int mt = 0; mt < 2; ++mt) {
            int rr = mt * 16 + lr;
            int byte = rr * 384 + t * 64 + lkq * 16;
            byte ^= (rr & 7) << 4;
            a[mt] = *(const bf16x8*)((const char*)gs + byte);
        }
#pragma unroll
        for (int nt = 0; nt < 3; ++nt)
            b[nt] = *(const bf16x8*)(Wt + ((size_t)((ntile0 + nt) * 12 + ktb + t) * 64 + lane) * 8);
    };
    auto MM = [&](bf16x8 (&a)[2], bf16x8 (&b)[3]) {
#pragma unroll
        for (int mt = 0; mt < 2; ++mt)
#pragma unroll
            for (int nt = 0; nt < 3; ++nt)
                acc[mt][nt] = __builtin_amdgcn_mfma_f32_16x16x32_bf16(a[mt], b[nt], acc[mt][nt], 0, 0, 0);
    };

    int crow = lkq * 4;

    if (kh == 1) {
        // ---- self-half GEMM first (no dependency on gather) ----
        LDself(0, a0, b0);
#pragma unroll
        for (int t = 0; t < 6; t += 2) {
            if (t + 1 < 6) LDself(t + 1, a1, b1);
            MM(a0, b0);
            if (t + 2 < 6) LDself(t + 2, a0, b0);
            if (t + 1 < 6) MM(a1, b1);
        }
#pragma unroll
        for (int mt = 0; mt < 2; ++mt)
#pragma unroll
            for (int r = 0; r < 4; ++r)
#pragma unroll
                for (int nt = 0; nt < 3; ++nt)
                    part[(mt * 16 + crow + r) * 192 + nb + nt * 16 + lr] = acc[mt][nt][r];
    } else {
        // ---- gather: 768 tasks over threads 0..255 (3 each) ----
#pragma unroll
        for (int it = 0; it < 3; ++it) {
            int task = tid + it * 256;
            int r = task / 24, f8 = task % 24;
            int bm = row0 + r;
            int b = bm / N3V, m = bm % N3V;
            const ushort* hb = src + (size_t)b * N3V * 192;
            float ga[8];
#pragma unroll
            for (int e = 0; e < 8; ++e) ga[e] = 0.f;
#pragma unroll
            for (int j = 0; j < 6; ++j) {
                float w = vals[m * 6 + j];
                bf16x8 v = *(const bf16x8*)(hb + (size_t)cols[m * 6 + j] * 192 + f8 * 8);
#pragma unroll
                for (int e = 0; e < 8; ++e) ga[e] += w * bf2f((ushort)v[e]);
            }
            bf16x8 o;
#pragma unroll
            for (int e = 0; e < 8; ++e) o[e] = (short)f2bf(ga[e]);
            int byte = r * 384 + f8 * 16;
            byte ^= (r & 7) << 4;
            *(bf16x8*)((char*)gs + byte) = o;
        }
    }
    __syncthreads();

    if (kh == 0) {
        // ---- g-half GEMM from LDS ----
        LDg(0, a0, b0);
#pragma unroll
        for (int t = 0; t < 6; t += 2) {
            if (t + 1 < 6) LDg(t + 1, a1, b1);
            MM(a0, b0);
            if (t + 2 < 6) LDg(t + 2, a0, b0);
            if (t + 1 < 6) MM(a1, b1);
        }
#pragma unroll
        for (int mt = 0; mt < 2; ++mt)
#pragma unroll
            for (int r = 0; r < 4; ++r) {
                int orow = row0 + mt * 16 + crow + r;
#pragma unroll
                for (int nt = 0; nt < 3; ++nt) {
                    int nn = nb + nt * 16 + lr;
                    float s = acc[mt][nt][r] + part[(mt * 16 + crow + r) * 192 + nn] + bias[nn];
                    s = fmaxf(s, 0.f);
                    if (ACT) s = 0.5f * (bf2f(hprev[(size_t)orow * 192 + nn]) + s);
                    outp[(size_t)orow * 192 + nn] = f2bf(s);
                }
            }
    }
}

// ---------------------------------------------------------------------------
// final head: block = 64 rows x 4 subs; each sub handles 48 k; quad shfl reduce
// ---------------------------------------------------------------------------
__global__ void head_a2(const ushort* __restrict__ y, const float* __restrict__ Wg,
                        const float* __restrict__ loopWg, float* __restrict__ t)
{
    int tid = threadIdx.x;
    int rloc = tid >> 2, sub = tid & 3;
    int bm = blockIdx.x * 64 + rloc;
    if (bm >= MTOT) return;
    float s[6];
#pragma unroll
    for (int c = 0; c < 6; ++c) s[c] = 0.f;
#pragma unroll
    for (int kk = 0; kk < 6; ++kk) {
        int kg = sub * 6 + kk;
        bf16x8 v = *(const bf16x8*)(y + (size_t)bm * 192 + kg * 8);
#pragma unroll
        for (int e = 0; e < 8; ++e) {
            float f = bf2f((ushort)v[e]);
            int k = kg * 8 + e;
            s[0] += f * Wg[k * 3 + 0];
            s[1] += f * Wg[k * 3 + 1];
            s[2] += f * Wg[k * 3 + 2];
            s[3] += f * loopWg[k * 3 + 0];
            s[4] += f * loopWg[k * 3 + 1];
            s[5] += f * loopWg[k * 3 + 2];
        }
    }
#pragma unroll
    for (int o = 1; o <= 2; o <<= 1)
#pragma unroll
        for (int c = 0; c < 6; ++c) s[c] += __shfl_xor(s[c], o);
    if (sub == 0) {
#pragma unroll
        for (int c = 0; c < 6; ++c) t[(size_t)bm * 6 + c] = s[c];
    }
}

__global__ void head_b(const float* __restrict__ t, const int* __restrict__ cols,
                       const float* __restrict__ vals, const float* __restrict__ bg,
                       float* __restrict__ out)
{
    int idx = blockIdx.x * 256 + threadIdx.x;
    if (idx >= MTOT * 3) return;
    int bm = idx / 3, c = idx % 3;
    int b = bm / N3V, m = bm % N3V;
    float s = 0.f;
#pragma unroll
    for (int j = 0; j < 6; ++j)
        s += vals[m * 6 + j] * t[((size_t)b * N3V + cols[m * 6 + j]) * 6 + c];
    s += t[(size_t)bm * 6 + 3 + c] + bg[c];
    out[idx] = s;
}

// ---------------------------------------------------------------------------
extern "C" void kernel_launch(void* const* d_in, const int* in_sizes, int n_in,
                              void* d_out, int out_size, void* d_ws, size_t ws_size,
                              hipStream_t stream)
{
    const float* x        = (const float*)d_in[0];
    const float* x2       = (const float*)d_in[1];
    const float* xh       = (const float*)d_in[2];
    const float* Wq       = (const float*)d_in[3];
    const float* bq       = (const float*)d_in[4];
    const float* Wk       = (const float*)d_in[5];
    const float* bk       = (const float*)d_in[6];
    const float* Wv       = (const float*)d_in[7];
    const float* bv       = (const float*)d_in[8];
    const float* adj      = (const float*)d_in[9];
    const int*   unpool   = (const int*)d_in[10];
    const float* W_in     = (const float*)d_in[11];
    const float* loopW_in = (const float*)d_in[12];
    const float* b_in     = (const float*)d_in[13];
    const float* res_W    = (const float*)d_in[14];
    const float* res_loopW= (const float*)d_in[15];
    const float* res_b    = (const float*)d_in[16];
    const float* W_out    = (const float*)d_in[17];
    const float* loopW_out= (const float*)d_in[18];
    const float* b_out    = (const float*)d_in[19];
    const float* Wg       = (const float*)d_in[20];
    const float* loopWg   = (const float*)d_in[21];
    const float* bg       = (const float*)d_in[22];
    float* out = (float*)d_out;

    char* ws = (char*)d_ws;
    size_t o = 0;
    auto alloc = [&](size_t bytes) { char* p = ws + o; o += (bytes + 255) & ~(size_t)255; return p; };
    float*  att  = (float*)alloc((size_t)M2 * 8 * 4);
    int*    cols = (int*)alloc((size_t)N3V * 6 * 4);
    float*  vals = (float*)alloc((size_t)N3V * 6 * 4);
    int*    eidx = (int*)alloc((size_t)N3V * 12 * 4);
    float*  ewgt = (float*)alloc((size_t)N3V * 12 * 4);
    int*    sidx = (int*)alloc((size_t)N3V * 2 * 4);
    ushort* F3   = (ushort*)alloc((size_t)M2 * KPAD2 * 2);
    ushort* wt_e = (ushort*)alloc((size_t)ENT_CHUNKS * 8 * 2);
    ushort* wt_r = (ushort*)alloc((size_t)RES_CHUNKS * 8 * 2);
    ushort* u2   = (ushort*)alloc((size_t)M2 * 384 * 2);
    ushort* h    = (ushort*)alloc((size_t)MTOT * 192 * 2);
    ushort* h2   = (ushort*)alloc((size_t)MTOT * 192 * 2);
    ushort* y    = (ushort*)alloc((size_t)MTOT * 192 * 2);
    float*  ts   = (float*)alloc((size_t)MTOT * 6 * 4);
    if (ws_size < o) return;

    attn_fused<<<dim3(NB, 10), 256, 0, stream>>>(x2, Wq, bq, Wk, bk, Wv, bv, att);
    adj_prep<<<N3V, 256, 0, stream>>>(adj, unpool, cols, vals, eidx, ewgt, sidx);
    build_F3<<<M2 / 16, 256, 0, stream>>>(x, xh, att, F3);
    prep_wt_frag<<<(ENT_CHUNKS + RES_CHUNKS + 255) / 256, 256, 0, stream>>>(
        W_in, loopW_in, res_W, res_loopW, W_out, loopW_out, wt_e, wt_r);

    // entry: u2 = F @ [W_in | loopW_in]   (M=9888, K=1216, k-split x2)
    gemm_entry<<<dim3((M2 + 63) / 64, 2), 512, 0, stream>>>(F3, wt_e, u2);
    combine_entry<<<(MTOT + 7) / 8, 192, 0, stream>>>(u2, eidx, ewgt, sidx, b_in, h);

    int gg = MTOT / 32;              // 1233
    ushort* cur = h;
    ushort* nxt = h2;
    for (int i = 0; i < 6; ++i) {
        const float* B0 = res_b + (size_t)(i * 2 + 0) * 192;
        const float* B1 = res_b + (size_t)(i * 2 + 1) * 192;
        const ushort* W0 = wt_r + (size_t)(i * 2 + 0) * (12 * 12 * 64 * 8);
        const ushort* W1 = wt_r + (size_t)(i * 2 + 1) * (12 * 12 * 64 * 8);
        gconv_fused<0><<<gg, 512, 0, stream>>>(cur, cols, vals, W0, B0, nullptr, y);
        gconv_fused<1><<<gg, 512, 0, stream>>>(y, cols, vals, W1, B1, cur, nxt);
        ushort* tmp = cur; cur = nxt; nxt = tmp;
    }

    // out conv (relu)
    gconv_fused<0><<<gg, 512, 0, stream>>>(cur, cols, vals,
        wt_r + (size_t)12 * (12 * 12 * 64 * 8), b_out, nullptr, y);

    head_a2<<<(MTOT + 63) / 64, 256, 0, stream>>>(y, Wg, loopWg, ts);
    head_b<<<(MTOT * 3 + 255) / 256, 256, 0, stream>>>(ts, cols, vals, bg, out);
}

// Round 15
// 412.545 us; speedup vs baseline: 1.7781x; 1.0326x over previous
//
#include <hip/hip_runtime.h>
#include <hip/hip_bf16.h>

#define NB 16
#define N2V 618
#define N3V 2466
#define FEAT 963
#define HID 192
#define IN_DIM 1163
#define KPAD2 1216         // 1163 padded to 38*32
#define ETILES 38
#define EHALF 19
#define MTOT (NB * N3V)    // 39456
#define M2   (NB * N2V)    // 9888

typedef __attribute__((ext_vector_type(8))) short bf16x8;
typedef __attribute__((ext_vector_type(4))) float f32x4;

__device__ __forceinline__ float bf2f(ushort u) {
    return __uint_as_float(((unsigned)u) << 16);
}
__device__ __forceinline__ ushort f2bf(float f) {   // round-to-nearest-even
    unsigned u = __float_as_uint(f);
    return (ushort)((u + 0x7FFFu + ((u >> 16) & 1u)) >> 16);
}
// bijective XCD-chunk swizzle (m204)
__device__ __forceinline__ int xcd_swz(int bid, int G) {
    int q = G >> 3, r = G & 7;
    int xcd = bid & 7, slot = bid >> 3;
    return (xcd < r) ? xcd * (q + 1) + slot : r * (q + 1) + (xcd - r) * q + slot;
}

// ---------------------------------------------------------------------------
// fused qkv + attention: block = (batch, 16 queries); 624 blocks.
// K,V computed from x2 directly into LDS; 16 lanes per query (39-iter key loop),
// online softmax, 4-step shfl merge within the 16-lane group.
// ---------------------------------------------------------------------------
__global__ __launch_bounds__(256) void attn_fused(
    const float* __restrict__ x2,
    const float* __restrict__ Wq, const float* __restrict__ bq,
    const float* __restrict__ Wk, const float* __restrict__ bk,
    const float* __restrict__ Wv, const float* __restrict__ bv,
    float* __restrict__ att)
{
    __shared__ float4 kv[N2V * 4];            // K: [0,2*N2V), V: [2*N2V,4*N2V)
    int b = blockIdx.x, qb = blockIdx.y;
    const float* x2b = x2 + (size_t)b * N2V * 3;

    for (int i = threadIdx.x; i < N2V; i += 256) {
        float c0 = x2b[i * 3], c1 = x2b[i * 3 + 1], c2 = x2b[i * 3 + 2];
        float kk[8], vv[8];
#pragma unroll
        for (int d = 0; d < 8; ++d) {
            kk[d] = bk[d] + c0 * Wk[8 + d] + c1 * Wk[16 + d] + c2 * Wk[24 + d];
            vv[d] = bv[d] + c0 * Wv[8 + d] + c1 * Wv[16 + d] + c2 * Wv[24 + d];
        }
        kv[i * 2]     = (float4){kk[0], kk[1], kk[2], kk[3]};
        kv[i * 2 + 1] = (float4){kk[4], kk[5], kk[6], kk[7]};
        kv[N2V * 2 + i * 2]     = (float4){vv[0], vv[1], vv[2], vv[3]};
        kv[N2V * 2 + i * 2 + 1] = (float4){vv[4], vv[5], vv[6], vv[7]};
    }
    __syncthreads();

    int ql = threadIdx.x >> 4, sub = threadIdx.x & 15;
    int qi = qb * 16 + ql;
    bool valid = qi < N2V;
    float qv[8];
#pragma unroll
    for (int d = 0; d < 8; ++d) qv[d] = 0.f;
    if (valid) {
        float c0 = x2b[qi * 3], c1 = x2b[qi * 3 + 1], c2 = x2b[qi * 3 + 2];
#pragma unroll
        for (int d = 0; d < 8; ++d)
            qv[d] = bq[d] + c0 * Wq[8 + d] + c1 * Wq[16 + d] + c2 * Wq[24 + d];
    }

    const float scale = 0.35355339059327373f;
    float m = -3.0e38f, lsum = 0.f, acc[8];
#pragma unroll
    for (int d = 0; d < 8; ++d) acc[d] = 0.f;

    for (int kk = sub; kk < N2V; kk += 16) {
        float4 k0 = kv[kk * 2], k1 = kv[kk * 2 + 1];
        float s = qv[0] * k0.x + qv[1] * k0.y + qv[2] * k0.z + qv[3] * k0.w
                + qv[4] * k1.x + qv[5] * k1.y + qv[6] * k1.z + qv[7] * k1.w;
        s *= scale;
        float nm = fmaxf(m, s);
        float corr = __expf(m - nm);
        float p = __expf(s - nm);
        lsum = lsum * corr + p;
        float4 v0 = kv[N2V * 2 + kk * 2], v1 = kv[N2V * 2 + kk * 2 + 1];
        acc[0] = acc[0] * corr + p * v0.x; acc[1] = acc[1] * corr + p * v0.y;
        acc[2] = acc[2] * corr + p * v0.z; acc[3] = acc[3] * corr + p * v0.w;
        acc[4] = acc[4] * corr + p * v1.x; acc[5] = acc[5] * corr + p * v1.y;
        acc[6] = acc[6] * corr + p * v1.z; acc[7] = acc[7] * corr + p * v1.w;
        m = nm;
    }
#pragma unroll
    for (int o = 1; o <= 8; o <<= 1) {
        float m2 = __shfl_xor(m, o);
        float l2 = __shfl_xor(lsum, o);
        float nm = fmaxf(m, m2);
        float c1 = __expf(m - nm), c2 = __expf(m2 - nm);
        lsum = lsum * c1 + l2 * c2;
#pragma unroll
        for (int d = 0; d < 8; ++d) {
            float a2 = __shfl_xor(acc[d], o);
            acc[d] = acc[d] * c1 + a2 * c2;
        }
        m = nm;
    }
    if (valid && sub == 0) {
#pragma unroll
        for (int d = 0; d < 8; ++d)
            att[((size_t)b * N2V + qi) * 8 + d] = acc[d] / lsum;
    }
}

// ---------------------------------------------------------------------------
// merged prep: blocks 0..N3V-1 = adjacency extraction; blocks >= N3V =
// fragment-layout weight transposes (entry + 13 res layers).
// ---------------------------------------------------------------------------
#define ENT_CHUNKS (24 * 38 * 64)
#define RES_CHUNKS (13 * 12 * 12 * 64)
#define WT_BLOCKS ((ENT_CHUNKS + RES_CHUNKS + 255) / 256)
__global__ void prep_all(const float* __restrict__ adj, const int* __restrict__ unpool,
                         int* __restrict__ cols, float* __restrict__ vals,
                         int* __restrict__ eidx, float* __restrict__ ew,
                         int* __restrict__ sidx,
                         const float* __restrict__ W_in, const float* __restrict__ loopW_in,
                         const float* __restrict__ res_W, const float* __restrict__ res_loopW,
                         const float* __restrict__ W_out, const float* __restrict__ loopW_out,
                         ushort* __restrict__ wt_e, ushort* __restrict__ wt_r)
{
    if (blockIdx.x >= N3V) {
        int idx = (blockIdx.x - N3V) * 256 + threadIdx.x;
        if (idx < ENT_CHUNKS) {
            int lane = idx & 63, r = idx >> 6;
            int kt = r % ETILES, ntile = r / ETILES;
            int n = ntile * 16 + (lane & 15);
            int k0 = kt * 32 + (lane >> 4) * 8;
            bf16x8 o;
#pragma unroll
            for (int j = 0; j < 8; ++j) {
                int k = k0 + j;
                float v = 0.f;
                if (k < IN_DIM) v = (n < 192) ? W_in[k * 192 + n] : loopW_in[k * 192 + (n - 192)];
                o[j] = (short)f2bf(v);
            }
            *(bf16x8*)(wt_e + (size_t)idx * 8) = o;
            return;
        }
        idx -= ENT_CHUNKS;
        if (idx >= RES_CHUNKS) return;
        int lane = idx & 63, r = idx >> 6;
        int kt = r % 12; r /= 12;
        int ntile = r % 12; int l = r / 12;
        const float* W = (l < 12) ? (res_W + (size_t)l * 192 * 192) : W_out;
        const float* L = (l < 12) ? (res_loopW + (size_t)l * 192 * 192) : loopW_out;
        int n = ntile * 16 + (lane & 15);
        int k0 = kt * 32 + (lane >> 4) * 8;
        bf16x8 o;
#pragma unroll
        for (int j = 0; j < 8; ++j) {
            int k2 = k0 + j;
            float v = (k2 < 192) ? W[k2 * 192 + n] : L[(k2 - 192) * 192 + n];
            o[j] = (short)f2bf(v);
        }
        *(bf16x8*)(wt_r + (size_t)idx * 8) = o;
        return;
    }

    int m = blockIdx.x;
    __shared__ int cnt;
    __shared__ int lc[8];
    __shared__ float lv[8];
    if (threadIdx.x == 0) cnt = 0;
    __syncthreads();
    for (int c = threadIdx.x; c < N3V; c += 256) {
        float a = adj[(size_t)m * N3V + c];
        if (a != 0.f) {
            int p = atomicAdd(&cnt, 1);
            if (p < 6) { lc[p] = c; lv[p] = a; }
        }
    }
    __syncthreads();
    if (threadIdx.x == 0) {
        int n = cnt < 6 ? cnt : 6;
        for (int i = 1; i < n; ++i) {
            int ci = lc[i]; float vi = lv[i]; int j = i - 1;
            while (j >= 0 && lc[j] > ci) { lc[j + 1] = lc[j]; lv[j + 1] = lv[j]; --j; }
            lc[j + 1] = ci; lv[j + 1] = vi;
        }
        int ne = 0;
        for (int i = 0; i < 6; ++i) {
            int c = (i < n) ? lc[i] : 0;
            float w = (i < n) ? lv[i] : 0.f;
            cols[m * 6 + i] = c;
            vals[m * 6 + i] = w;
            if (i < n) {
                if (c < N2V) { eidx[m * 12 + ne] = c; ew[m * 12 + ne] = w; ++ne; }
                else {
                    int jj = c - N2V;
                    eidx[m * 12 + ne] = unpool[2 * jj];     ew[m * 12 + ne] = 0.5f * w; ++ne;
                    eidx[m * 12 + ne] = unpool[2 * jj + 1]; ew[m * 12 + ne] = 0.5f * w; ++ne;
                }
            }
        }
        for (; ne < 12; ++ne) { eidx[m * 12 + ne] = 0; ew[m * 12 + ne] = 0.f; }
        if (m < N2V) { sidx[m * 2] = m; sidx[m * 2 + 1] = -1; }
        else {
            int j = m - N2V;
            sidx[m * 2] = unpool[2 * j];
            sidx[m * 2 + 1] = unpool[2 * j + 1];
        }
    }
}

// ---------------------------------------------------------------------------
// F in FRAGMENT layout: F3[rt][kt][lane][8], row = rt*16+(lane&15),
// k = kt*32+(lane>>4)*8+j. One block per row-tile (618); writes coalesced.
// ---------------------------------------------------------------------------
__global__ void build_F3(const float* __restrict__ x, const float* __restrict__ xh,
                         const float* __restrict__ att, ushort* __restrict__ F3)
{
    int rt = blockIdx.x;                       // 0..617
    for (int c = threadIdx.x; c < ETILES * 64; c += 256) {
        int kt = c >> 6, lane = c & 63;
        int row = rt * 16 + (lane & 15);       // < M2
        int k0 = kt * 32 + (lane >> 4) * 8;
        bf16x8 o;
#pragma unroll
        for (int j = 0; j < 8; ++j) {
            int k = k0 + j;
            float v = 0.f;
            if (k < FEAT) v = x[(size_t)row * FEAT + k];
            else if (k < FEAT + HID) v = xh[(size_t)row * HID + (k - FEAT)];
            else if (k < IN_DIM) v = att[(size_t)row * 8 + (k - FEAT - HID)];
            o[j] = (short)f2bf(v);
        }
        *(bf16x8*)(F3 + ((size_t)(rt * ETILES + kt) * 64 + lane) * 8) = o;
    }
}

// ---------------------------------------------------------------------------
// entry GEMM, K-split x2, fragment-layout A and B (1KB coalesced wave loads).
// 512 thr (8 waves); block 64 rows x 192 cols; grid (155, 2).
// ---------------------------------------------------------------------------
__global__ __launch_bounds__(512) void gemm_entry(
    const ushort* __restrict__ F3, const ushort* __restrict__ Wt,
    ushort* __restrict__ u2)
{
    __shared__ float part[64 * 192];   // 48 KB

    int tid = threadIdx.x;
    int wave = tid >> 6, lane = tid & 63;
    int kh = wave >> 2, w4 = wave & 3;
    int lr = lane & 15, lkq = lane >> 4;
    int row0 = blockIdx.x * 64;
    int rt0 = blockIdx.x * 4;
    int lnb = w4 * 48;
    int nb = blockIdx.y * 192 + lnb;
    int ntile0 = nb >> 4;
    int tbeg = kh * EHALF, tend = tbeg + EHALF;

    int rts[4];
#pragma unroll
    for (int mt = 0; mt < 4; ++mt) {
        int rt = rt0 + mt;
        rts[mt] = (rt < M2 / 16) ? rt : (M2 / 16 - 1);
    }

    f32x4 acc[4][3];
#pragma unroll
    for (int mt = 0; mt < 4; ++mt)
#pragma unroll
        for (int nt = 0; nt < 3; ++nt) acc[mt][nt] = (f32x4){0.f, 0.f, 0.f, 0.f};

    bf16x8 a0[4], b0[3], a1[4], b1[3];
    auto LD = [&](int t, bf16x8 (&a)[4], bf16x8 (&b)[3]) {
#pragma unroll
        for (int mt = 0; mt < 4; ++mt)
            a[mt] = *(const bf16x8*)(F3 + ((size_t)(rts[mt] * ETILES + t) * 64 + lane) * 8);
#pragma unroll
        for (int nt = 0; nt < 3; ++nt)
            b[nt] = *(const bf16x8*)(Wt + ((size_t)((ntile0 + nt) * ETILES + t) * 64 + lane) * 8);
    };
    auto MM = [&](bf16x8 (&a)[4], bf16x8 (&b)[3]) {
#pragma unroll
        for (int mt = 0; mt < 4; ++mt)
#pragma unroll
            for (int nt = 0; nt < 3; ++nt)
                acc[mt][nt] = __builtin_amdgcn_mfma_f32_16x16x32_bf16(a[mt], b[nt], acc[mt][nt], 0, 0, 0);
    };

    LD(tbeg, a0, b0);
    for (int t = tbeg; t < tend; t += 2) {
        if (t + 1 < tend) LD(t + 1, a1, b1);
        MM(a0, b0);
        if (t + 2 < tend) LD(t + 2, a0, b0);
        if (t + 1 < tend) MM(a1, b1);
    }

    int crow = lkq * 4;
    if (kh == 1) {
#pragma unroll
        for (int mt = 0; mt < 4; ++mt)
#pragma unroll
            for (int r = 0; r < 4; ++r)
#pragma unroll
                for (int nt = 0; nt < 3; ++nt)
                    part[(mt * 16 + crow + r) * 192 + lnb + nt * 16 + lr] = acc[mt][nt][r];
    }
    __syncthreads();
    if (kh == 0) {
#pragma unroll
        for (int mt = 0; mt < 4; ++mt)
#pragma unroll
            for (int r = 0; r < 4; ++r) {
                int orow = row0 + mt * 16 + crow + r;
                if (orow < M2) {
#pragma unroll
                    for (int nt = 0; nt < 3; ++nt) {
                        float s = acc[mt][nt][r] + part[(mt * 16 + crow + r) * 192 + lnb + nt * 16 + lr];
                        u2[(size_t)orow * 384 + nb + nt * 16 + lr] = f2bf(s);
                    }
                }
            }
    }
}

// ---------------------------------------------------------------------------
// entry combine: h = relu( sum_i ew*Pw[eidx] + mid(Pl over sidx) + bias )
// ---------------------------------------------------------------------------
__global__ void combine_entry(const ushort* __restrict__ u2, const int* __restrict__ eidx,
                              const float* __restrict__ ew, const int* __restrict__ sidx,
                              const float* __restrict__ bias, ushort* __restrict__ h)
{
    int lb = xcd_swz(blockIdx.x, gridDim.x);
    int tid = threadIdx.x;
    int rloc = tid / 24, f8 = tid % 24;
    int bm = lb * 8 + rloc;
    if (bm >= MTOT) return;
    int b = bm / N3V, n = bm % N3V;
    const ushort* base = u2 + (size_t)b * N2V * 384;

    float acc[8];
#pragma unroll
    for (int e = 0; e < 8; ++e) acc[e] = 0.f;
#pragma unroll
    for (int i = 0; i < 12; ++i) {
        float w = ew[n * 12 + i];
        bf16x8 v = *(const bf16x8*)(base + (size_t)eidx[n * 12 + i] * 384 + f8 * 8);
#pragma unroll
        for (int e = 0; e < 8; ++e) acc[e] += w * bf2f((ushort)v[e]);
    }
    int p0 = sidx[n * 2], p1 = sidx[n * 2 + 1];
    bf16x8 s0 = *(const bf16x8*)(base + (size_t)p0 * 384 + 192 + f8 * 8);
    if (p1 >= 0) {
        bf16x8 s1 = *(const bf16x8*)(base + (size_t)p1 * 384 + 192 + f8 * 8);
#pragma unroll
        for (int e = 0; e < 8; ++e) acc[e] += 0.5f * (bf2f((ushort)s0[e]) + bf2f((ushort)s1[e]));
    } else {
#pragma unroll
        for (int e = 0; e < 8; ++e) acc[e] += bf2f((ushort)s0[e]);
    }
    bf16x8 o;
#pragma unroll
    for (int e = 0; e < 8; ++e)
        o[e] = (short)f2bf(fmaxf(acc[e] + bias[f8 * 8 + e], 0.f));
    *(bf16x8*)(h + (size_t)bm * 192 + f8 * 8) = o;
}

// ---------------------------------------------------------------------------
// fused res GConv, WAVE-SPECIALIZED, single barrier (r14 winner structure).
// ---------------------------------------------------------------------------
template <int ACT>
__global__ __launch_bounds__(512) void gconv_fused(
    const ushort* __restrict__ src, const int* __restrict__ cols,
    const float* __restrict__ vals, const ushort* __restrict__ Wt,
    const float* __restrict__ bias, const ushort* __restrict__ hprev,
    ushort* __restrict__ outp)
{
    __shared__ ushort gs[32 * 192];    // 12 KB, XOR-swizzled
    __shared__ float part[32 * 192];   // 24 KB

    int lb = xcd_swz(blockIdx.x, gridDim.x);
    int tid = threadIdx.x;
    int row0 = lb * 32;                // MTOT % 32 == 0

    int wave = tid >> 6, lane = tid & 63;
    int kh = wave >> 2, w4 = wave & 3;
    int lr = lane & 15, lkq = lane >> 4, lk = lkq * 8;
    int nb = w4 * 48;
    int ntile0 = nb >> 4;
    int rows[2] = { row0 + lr, row0 + 16 + lr };
    int ktb = kh * 6;

    f32x4 acc[2][3];
#pragma unroll
    for (int mt = 0; mt < 2; ++mt)
#pragma unroll
        for (int nt = 0; nt < 3; ++nt) acc[mt][nt] = (f32x4){0.f, 0.f, 0.f, 0.f};

    bf16x8 a0[2], b0[3], a1[2], b1[3];
    auto LDself = [&](int t, bf16x8 (&a)[2], bf16x8 (&b)[3]) {
        int kk = t * 32 + lk;
#pragma unroll
        for (int mt = 0; mt < 2; ++mt)
            a[mt] = *(const bf16x8*)(src + (size_t)rows[mt] * 192 + kk);
#pragma unroll
        for (int nt = 0; nt < 3; ++nt)
            b[nt] = *(const bf16x8*)(Wt + ((size_t)((ntile0 + nt) * 12 + ktb + t) * 64 + lane) * 8);
    };
    auto LDg = [&](int t, bf16x8 (&a)[2], bf16x8 (&b)[3]) {
#pragma unroll
        for (int mt = 0; mt < 2; ++mt) {
            int rr = mt * 16 + lr;
            int byte = rr * 384 + t * 64 + lkq * 16;
            byte ^= (rr & 7) << 4;
            a[mt] = *(const bf16x8*)((const char*)gs + byte);
        }
#pragma unroll
        for (int nt = 0; nt < 3; ++nt)
            b[nt] = *(const bf16x8*)(Wt + ((size_t)((ntile0 + nt) * 12 + ktb + t) * 64 + lane) * 8);
    };
    auto MM = [&](bf16x8 (&a)[2], bf16x8 (&b)[3]) {
#pragma unroll
        for (int mt = 0; mt < 2; ++mt)
#pragma unroll
            for (int nt = 0; nt < 3; ++nt)
                acc[mt][nt] = __builtin_amdgcn_mfma_f32_16x16x32_bf16(a[mt], b[nt], acc[mt][nt], 0, 0, 0);
    };

    int crow = lkq * 4;

    if (kh == 1) {
        LDself(0, a0, b0);
#pragma unroll
        for (int t = 0; t < 6; t += 2) {
            if (t + 1 < 6) LDself(t + 1, a1, b1);
            MM(a0, b0);
            if (t + 2 < 6) LDself(t + 2, a0, b0);
            if (t + 1 < 6) MM(a1, b1);
        }
#pragma unroll
        for (int mt = 0; mt < 2; ++mt)
#pragma unroll
            for (int r = 0; r < 4; ++r)
#pragma unroll
                for (int nt = 0; nt < 3; ++nt)
                    part[(mt * 16 + crow + r) * 192 + nb + nt * 16 + lr] = acc[mt][nt][r];
    } else {
#pragma unroll
        for (int it = 0; it < 3; ++it) {
            int task = tid + it * 256;
            int r = task / 24, f8 = task % 24;
            int bm = row0 + r;
            int b = bm / N3V, m = bm % N3V;
            const ushort* hb = src + (size_t)b * N3V * 192;
            float ga[8];
#pragma unroll
            for (int e = 0; e < 8; ++e) ga[e] = 0.f;
#pragma unroll
            for (int j = 0; j < 6; ++j) {
                float w = vals[m * 6 + j];
                bf16x8 v = *(const bf16x8*)(hb + (size_t)cols[m * 6 + j] * 192 + f8 * 8);
#pragma unroll
                for (int e = 0; e < 8; ++e) ga[e] += w * bf2f((ushort)v[e]);
            }
            bf16x8 o;
#pragma unroll
            for (int e = 0; e < 8; ++e) o[e] = (short)f2bf(ga[e]);
            int byte = r * 384 + f8 * 16;
            byte ^= (r & 7) << 4;
            *(bf16x8*)((char*)gs + byte) = o;
        }
    }
    __syncthreads();

    if (kh == 0) {
        LDg(0, a0, b0);
#pragma unroll
        for (int t = 0; t < 6; t += 2) {
            if (t + 1 < 6) LDg(t + 1, a1, b1);
            MM(a0, b0);
            if (t + 2 < 6) LDg(t + 2, a0, b0);
            if (t + 1 < 6) MM(a1, b1);
        }
#pragma unroll
        for (int mt = 0; mt < 2; ++mt)
#pragma unroll
            for (int r = 0; r < 4; ++r) {
                int orow = row0 + mt * 16 + crow + r;
#pragma unroll
                for (int nt = 0; nt < 3; ++nt) {
                    int nn = nb + nt * 16 + lr;
                    float s = acc[mt][nt][r] + part[(mt * 16 + crow + r) * 192 + nn] + bias[nn];
                    s = fmaxf(s, 0.f);
                    if (ACT) s = 0.5f * (bf2f(hprev[(size_t)orow * 192 + nn]) + s);
                    outp[(size_t)orow * 192 + nn] = f2bf(s);
                }
            }
    }
}

// ---------------------------------------------------------------------------
// final head: block = 64 rows x 4 subs; each sub handles 48 k; quad shfl reduce
// ---------------------------------------------------------------------------
__global__ void head_a2(const ushort* __restrict__ y, const float* __restrict__ Wg,
                        const float* __restrict__ loopWg, float* __restrict__ t)
{
    int tid = threadIdx.x;
    int rloc = tid >> 2, sub = tid & 3;
    int bm = blockIdx.x * 64 + rloc;
    if (bm >= MTOT) return;
    float s[6];
#pragma unroll
    for (int c = 0; c < 6; ++c) s[c] = 0.f;
#pragma unroll
    for (int kk = 0; kk < 6; ++kk) {
        int kg = sub * 6 + kk;
        bf16x8 v = *(const bf16x8*)(y + (size_t)bm * 192 + kg * 8);
#pragma unroll
        for (int e = 0; e < 8; ++e) {
            float f = bf2f((ushort)v[e]);
            int k = kg * 8 + e;
            s[0] += f * Wg[k * 3 + 0];
            s[1] += f * Wg[k * 3 + 1];
            s[2] += f * Wg[k * 3 + 2];
            s[3] += f * loopWg[k * 3 + 0];
            s[4] += f * loopWg[k * 3 + 1];
            s[5] += f * loopWg[k * 3 + 2];
        }
    }
#pragma unroll
    for (int o = 1; o <= 2; o <<= 1)
#pragma unroll
        for (int c = 0; c < 6; ++c) s[c] += __shfl_xor(s[c], o);
    if (sub == 0) {
#pragma unroll
        for (int c = 0; c < 6; ++c) t[(size_t)bm * 6 + c] = s[c];
    }
}

__global__ void head_b(const float* __restrict__ t, const int* __restrict__ cols,
                       const float* __restrict__ vals, const float* __restrict__ bg,
                       float* __restrict__ out)
{
    int idx = blockIdx.x * 256 + threadIdx.x;
    if (idx >= MTOT * 3) return;
    int bm = idx / 3, c = idx % 3;
    int b = bm / N3V, m = bm % N3V;
    float s = 0.f;
#pragma unroll
    for (int j = 0; j < 6; ++j)
        s += vals[m * 6 + j] * t[((size_t)b * N3V + cols[m * 6 + j]) * 6 + c];
    s += t[(size_t)bm * 6 + 3 + c] + bg[c];
    out[idx] = s;
}

// ---------------------------------------------------------------------------
extern "C" void kernel_launch(void* const* d_in, const int* in_sizes, int n_in,
                              void* d_out, int out_size, void* d_ws, size_t ws_size,
                              hipStream_t stream)
{
    const float* x        = (const float*)d_in[0];
    const float* x2       = (const float*)d_in[1];
    const float* xh       = (const float*)d_in[2];
    const float* Wq       = (const float*)d_in[3];
    const float* bq       = (const float*)d_in[4];
    const float* Wk       = (const float*)d_in[5];
    const float* bk       = (const float*)d_in[6];
    const float* Wv       = (const float*)d_in[7];
    const float* bv       = (const float*)d_in[8];
    const float* adj      = (const float*)d_in[9];
    const int*   unpool   = (const int*)d_in[10];
    const float* W_in     = (const float*)d_in[11];
    const float* loopW_in = (const float*)d_in[12];
    const float* b_in     = (const float*)d_in[13];
    const float* res_W    = (const float*)d_in[14];
    const float* res_loopW= (const float*)d_in[15];
    const float* res_b    = (const float*)d_in[16];
    const float* W_out    = (const float*)d_in[17];
    const float* loopW_out= (const float*)d_in[18];
    const float* b_out    = (const float*)d_in[19];
    const float* Wg       = (const float*)d_in[20];
    const float* loopWg   = (const float*)d_in[21];
    const float* bg       = (const float*)d_in[22];
    float* out = (float*)d_out;

    char* ws = (char*)d_ws;
    size_t o = 0;
    auto alloc = [&](size_t bytes) { char* p = ws + o; o += (bytes + 255) & ~(size_t)255; return p; };
    float*  att  = (float*)alloc((size_t)M2 * 8 * 4);
    int*    cols = (int*)alloc((size_t)N3V * 6 * 4);
    float*  vals = (float*)alloc((size_t)N3V * 6 * 4);
    int*    eidx = (int*)alloc((size_t)N3V * 12 * 4);
    float*  ewgt = (float*)alloc((size_t)N3V * 12 * 4);
    int*    sidx = (int*)alloc((size_t)N3V * 2 * 4);
    ushort* F3   = (ushort*)alloc((size_t)M2 * KPAD2 * 2);
    ushort* wt_e = (ushort*)alloc((size_t)ENT_CHUNKS * 8 * 2);
    ushort* wt_r = (ushort*)alloc((size_t)RES_CHUNKS * 8 * 2);
    ushort* u2   = (ushort*)alloc((size_t)M2 * 384 * 2);
    ushort* h    = (ushort*)alloc((size_t)MTOT * 192 * 2);
    ushort* h2   = (ushort*)alloc((size_t)MTOT * 192 * 2);
    ushort* y    = (ushort*)alloc((size_t)MTOT * 192 * 2);
    float*  ts   = (float*)alloc((size_t)MTOT * 6 * 4);
    if (ws_size < o) return;

    attn_fused<<<dim3(NB, 39), 256, 0, stream>>>(x2, Wq, bq, Wk, bk, Wv, bv, att);
    prep_all<<<N3V + WT_BLOCKS, 256, 0, stream>>>(adj, unpool, cols, vals, eidx, ewgt, sidx,
        W_in, loopW_in, res_W, res_loopW, W_out, loopW_out, wt_e, wt_r);
    build_F3<<<M2 / 16, 256, 0, stream>>>(x, xh, att, F3);

    // entry: u2 = F @ [W_in | loopW_in]   (M=9888, K=1216, k-split x2)
    gemm_entry<<<dim3((M2 + 63) / 64, 2), 512, 0, stream>>>(F3, wt_e, u2);
    combine_entry<<<(MTOT + 7) / 8, 192, 0, stream>>>(u2, eidx, ewgt, sidx, b_in, h);

    int gg = MTOT / 32;              // 1233
    ushort* cur = h;
    ushort* nxt = h2;
    for (int i = 0; i < 6; ++i) {
        const float* B0 = res_b + (size_t)(i * 2 + 0) * 192;
        const float* B1 = res_b + (size_t)(i * 2 + 1) * 192;
        const ushort* W0 = wt_r + (size_t)(i * 2 + 0) * (12 * 12 * 64 * 8);
        const ushort* W1 = wt_r + (size_t)(i * 2 + 1) * (12 * 12 * 64 * 8);
        gconv_fused<0><<<gg, 512, 0, stream>>>(cur, cols, vals, W0, B0, nullptr, y);
        gconv_fused<1><<<gg, 512, 0, stream>>>(y, cols, vals, W1, B1, cur, nxt);
        ushort* tmp = cur; cur = nxt; nxt = tmp;
    }

    // out conv (relu)
    gconv_fused<0><<<gg, 512, 0, stream>>>(cur, cols, vals,
        wt_r + (size_t)12 * (12 * 12 * 64 * 8), b_out, nullptr, y);

    head_a2<<<(MTOT + 63) / 64, 256, 0, stream>>>(y, Wg, loopWg, ts);
    head_b<<<(MTOT * 3 + 255) / 256, 256, 0, stream>>>(ts, cols, vals, bg, out);
}